// Round 1
// baseline (1365.211 us; speedup 1.0000x reference)
//
#include <hip/hip_runtime.h>
#include <hip/hip_bf16.h>
#include <math.h>

// ASTGCN block, MI355X. Round 7: k_fuse occupancy fix — weights no longer
// staged in LDS (they are global/L1-resident, shared by all blocks); k_prepW
// repacks them so every weight fetch is one coalesced dword/qword load.
// LDS/block 77824->36864 B => 2->4 blocks/CU. __launch_bounds__(256,4) pins
// VGPR <= 128 so LDS stays the (relaxed) limit.

namespace {

constexpr int B = 16, N = 1024, F = 32, T = 24, CC = 64, CT = 64;
constexpr int FT = F * T;     // 768
constexpr int CTT = CT * T;   // 1536

using f32x4  = __attribute__((ext_vector_type(4))) float;
using short8 = __attribute__((ext_vector_type(8))) short;

__device__ __forceinline__ float b2f(__hip_bfloat16 v) { return __bfloat162float(v); }
__device__ __forceinline__ unsigned short f2bu(float x) {   // fp32 -> bf16 bits, RNE
  union { float f; unsigned u; } c; c.f = x;
  unsigned u = c.u;
  return (unsigned short)((u + 0x7FFFu + ((u >> 16) & 1u)) >> 16);
}
__device__ __forceinline__ float us2f(unsigned short u) {   // bf16 bits -> fp32
  union { unsigned u; float f; } c; c.u = ((unsigned)u) << 16; return c.f;
}

// ---------------- temporal attention ----------------
__global__ void k_lhs_t(const float* x, const float* U1, float* lhst) {
  int bi = blockIdx.x;                 // (b*T+t)*F + f
  int f = bi % F; int t = (bi / F) % T; int b = bi / (F * T);
  int tid = threadIdx.x;
  float acc = 0.f;
  for (int n = tid; n < N; n += 64)
    acc += x[(((size_t)b * N + n) * F + f) * T + t] * U1[n];
  #pragma unroll
  for (int off = 32; off > 0; off >>= 1) acc += __shfl_down(acc, off);
  if (tid == 0) lhst[bi] = acc;
}

__global__ void k_lhs2(const float* lhst, const float* U2, float* lhs2) {
  __shared__ float ls[F];
  int tid = threadIdx.x;
  int id = blockIdx.x * 256 + tid;   // (b*T+t)*N + n
  int n = id % N; int bt = id / N;
  if (tid < F) ls[tid] = lhst[bt * F + tid];
  __syncthreads();
  float acc = 0.f;
  #pragma unroll
  for (int f = 0; f < F; ++f) acc += ls[f] * U2[f * N + n];
  lhs2[id] = acc;
}

__global__ void k_fx(const float* x, const float* U3, const float* W3,
                     float* rhst, float* w3x) {
  __shared__ float u3s[F], w3s[F];
  int tid = threadIdx.x;
  if (tid < F) { u3s[tid] = U3[tid]; w3s[tid] = W3[tid]; }
  __syncthreads();
  int id = blockIdx.x * 256 + tid;     // (b*N+n)*T + t
  int t = id % T; int bn = id / T;
  float au = 0.f, aw = 0.f;
  #pragma unroll
  for (int f = 0; f < F; ++f) {
    float v = x[((size_t)bn * F + f) * T + t];
    au += u3s[f] * v; aw += w3s[f] * v;
  }
  rhst[id] = au; w3x[id] = aw;
}

__global__ void k_Elog(const float* lhs2, const float* rhst, float* Elog) {
  int bi = blockIdx.x;                 // (b*T+t)*T + s
  int s = bi % T; int t = (bi / T) % T; int b = bi / (T * T);
  int tid = threadIdx.x;
  float acc = 0.f;
  for (int n = tid; n < N; n += 64)
    acc += lhs2[(b * T + t) * N + n] * rhst[(b * N + n) * T + s];
  #pragma unroll
  for (int off = 32; off > 0; off >>= 1) acc += __shfl_down(acc, off);
  if (tid == 0) Elog[bi] = acc;
}

__global__ void k_Esm(const float* Elog, float* E) {
  int b = blockIdx.x; int s = threadIdx.x;
  if (s >= T) return;
  float mx = -1e30f;
  for (int t = 0; t < T; ++t) mx = fmaxf(mx, Elog[(b * T + t) * T + s]);
  float sum = 0.f;
  for (int t = 0; t < T; ++t) sum += expf(Elog[(b * T + t) * T + s] - mx);
  float inv = 1.f / sum;
  for (int t = 0; t < T; ++t)
    E[(b * T + t) * T + s] = expf(Elog[(b * T + t) * T + s] - mx) * inv;
}

__global__ void k_EW1(const float* E, const float* W1, float* EW1) {
  int b = blockIdx.x; int t = threadIdx.x;
  if (t >= T) return;
  float acc = 0.f;
  for (int s = 0; s < T; ++s) acc += E[(b * T + t) * T + s] * W1[s];
  EW1[b * T + t] = acc;
}

// ---------------- spatial attention ----------------
__global__ void k_tmp1x(const float* x, const float* EW1, float* tmp1) {
  __shared__ float ew[T];
  int tid = threadIdx.x;
  int id = blockIdx.x * 256 + tid;       // (b*N+n)*F + f
  int b = id / (N * F);
  if (tid < T) ew[tid] = EW1[b * T + tid];
  __syncthreads();
  const float* xr = x + (size_t)id * T;
  float acc = 0.f;
  #pragma unroll
  for (int t = 0; t < T; ++t) acc += xr[t] * ew[t];
  tmp1[id] = acc;
}

__global__ void k_lhs_s(const float* tmp1, const float* W2, float* lhss) {
  int id = blockIdx.x * 256 + threadIdx.x;
  int t = id % T; int bn = id / T;
  float acc = 0.f;
  #pragma unroll
  for (int f = 0; f < F; ++f) acc += tmp1[bn * F + f] * W2[f * T + t];
  lhss[id] = acc;
}

__global__ void k_rhss(const float* w3x, const float* E, float* rhss) {
  __shared__ float Ec[T];
  int tid = threadIdx.x;
  int id = blockIdx.x * 256 + tid;       // (b*T+t)*N + m
  int m = id % N; int t = (id / N) % T; int b = id / (N * T);
  if (tid < T) Ec[tid] = E[(b * T + tid) * T + t];
  __syncthreads();
  const float* wr = w3x + ((size_t)b * N + m) * T;
  float acc = 0.f;
  #pragma unroll
  for (int tp = 0; tp < T; ++tp) acc += wr[tp] * Ec[tp];
  rhss[id] = acc;
}

__global__ void k_Slog(const float* lhss, const float* rhss, __hip_bfloat16* S) {
  __shared__ float rt[T][256];
  __shared__ float lt[16][T];
  int m0 = blockIdx.x * 256, n0 = blockIdx.y * 16, b = blockIdx.z;
  int tid = threadIdx.x;
  for (int t = 0; t < T; ++t) rt[t][tid] = rhss[((size_t)b * T + t) * N + m0 + tid];
  for (int i = tid; i < 16 * T; i += 256) {
    int n = i / T, t = i % T;
    lt[n][t] = lhss[((size_t)b * N + n0 + n) * T + t];
  }
  __syncthreads();
  #pragma unroll 4
  for (int n = 0; n < 16; ++n) {
    float acc = 0.f;
    #pragma unroll
    for (int t = 0; t < T; ++t) acc += lt[n][t] * rt[t][tid];
    S[((size_t)b * N + n0 + n) * N + m0 + tid] = __float2bfloat16(acc);
  }
}

__global__ void k_Ssm3(__hip_bfloat16* S) {
  int m = blockIdx.x * 256 + threadIdx.x; int b = blockIdx.y;
  size_t base = (size_t)b * N * N + m;
  float mx = -1e30f;
  for (int n = 0; n < N; ++n) mx = fmaxf(mx, b2f(S[base + (size_t)n * N]));
  float sum = 0.f;
  for (int n = 0; n < N; ++n) sum += expf(b2f(S[base + (size_t)n * N]) - mx);
  float inv = 1.f / sum;
  for (int n = 0; n < N; ++n) {
    size_t i = base + (size_t)n * N;
    S[i] = __float2bfloat16(expf(b2f(S[i]) - mx) * inv);
  }
}

// ---------------- GEMM operand prep (transpose to n-contiguous bf16) --------
// Abf[(k*Bc+bl)][m][n] = bf16(cheb[k,n,m] * S[b,n,m]); grid (N/64, N/64, 3*Bc)
__global__ __launch_bounds__(256) void k_prepA(const float* cheb,
                                               const __hip_bfloat16* S,
                                               unsigned short* Abf,
                                               int Bc, int b0) {
  __shared__ float Tl[64][65];
  int z = blockIdx.z;
  int k = z / Bc, bl = z % Bc, b = b0 + bl;
  int n0 = blockIdx.x * 64, m0 = blockIdx.y * 64;
  int tid = threadIdx.x;
  int j = tid & 63, i4 = tid >> 6;
  #pragma unroll
  for (int it = 0; it < 16; ++it) {
    int i = it * 4 + i4;
    Tl[i][j] = cheb[((size_t)k * N + n0 + i) * N + m0 + j] *
               b2f(S[((size_t)b * N + n0 + i) * N + m0 + j]);
  }
  __syncthreads();
  int i2 = (tid & 31) * 2, j8 = tid >> 5;
  #pragma unroll
  for (int it = 0; it < 8; ++it) {
    int jj = it * 8 + j8;
    unsigned u = (unsigned)f2bu(Tl[i2][jj]) | ((unsigned)f2bu(Tl[i2 + 1][jj]) << 16);
    *(unsigned*)&Abf[((size_t)z * N + m0 + jj) * N + n0 + i2] = u;
  }
}

// xT[bl][c][n] = bf16(x[b,n,c]); grid (N/64, FT/64=12, Bc)
__global__ __launch_bounds__(256) void k_prepX(const float* x, unsigned short* xT,
                                               int b0) {
  __shared__ float Tl[64][65];
  int bl = blockIdx.z, b = b0 + bl;
  int n0 = blockIdx.x * 64, c0 = blockIdx.y * 64;
  int tid = threadIdx.x;
  int j = tid & 63, i4 = tid >> 6;
  #pragma unroll
  for (int it = 0; it < 16; ++it) {
    int i = it * 4 + i4;
    Tl[i][j] = x[((size_t)b * N + n0 + i) * FT + c0 + j];
  }
  __syncthreads();
  int i2 = (tid & 31) * 2, j8 = tid >> 5;
  #pragma unroll
  for (int it = 0; it < 8; ++it) {
    int jj = it * 8 + j8;
    unsigned u = (unsigned)f2bu(Tl[i2][jj]) | ((unsigned)f2bu(Tl[i2 + 1][jj]) << 16);
    *(unsigned*)&xT[((size_t)bl * FT + c0 + jj) * N + n0 + i2] = u;
  }
}

// weights -> bf16, packed for direct (non-LDS) coalesced reads in k_fuse.
// Layout (ushort indices):
//   Theta pairs : [(kf>>1)*128 + o*2 + (kf&1)]          0     .. 6143
//   tconv quads : [6144 + (cc*64 + o)*4 + j] (j=3 pad)  6144  .. 22527
//   rconv pairs : [22528 + (f>>1)*128 + o*2 + (f&1)]    22528 .. 24575
__global__ void k_prepW(const float* Theta, const float* tcw, const float* rcw,
                        unsigned short* wbf) {
  int tid = threadIdx.x;
  for (int g = tid; g < 96 * 64; g += 256) {
    int kf = g >> 6, o = g & 63;
    wbf[(kf >> 1) * 128 + o * 2 + (kf & 1)] = f2bu(Theta[g]);
  }
  for (int g = tid; g < 64 * 64 * 4; g += 256) {
    int cc = g >> 8, o = (g >> 2) & 63, j = g & 3;
    wbf[6144 + g] = (j < 3) ? f2bu(tcw[o * 192 + cc * 3 + j]) : (unsigned short)0;
  }
  for (int g = tid; g < 32 * 64; g += 256) {
    int f = g >> 6, o = g & 63;
    wbf[22528 + (f >> 1) * 128 + o * 2 + (f & 1)] = f2bu(rcw[o * 32 + f]);
  }
}

// ---------------- Chebyshev contraction: fused 3-k MFMA bf16 v2 -------------
// Both operands bf16, n-contiguous. Staging = pure 16B copies.
// Tile 64m x 128c x 64n; waves 2x2 (32m x 64c each). grid (6, 16, Bc).
__global__ __launch_bounds__(256) void k_gemm3(const unsigned short* Abf,
                                               const unsigned short* xT,
                                               float* rk, size_t kstride,
                                               int Bc) {
  __shared__ __align__(16) unsigned short A_l[3 * 64 * 72];   // 27648 B
  __shared__ __align__(16) unsigned short X_l[128 * 72];      // 18432 B
  int bl = blockIdx.z;
  int m0 = blockIdx.y * 64, c0 = blockIdx.x * 128;
  int tid = threadIdx.x;
  int lane = tid & 63, w = tid >> 6;
  int l15 = lane & 15, quad = lane >> 4;
  int wmi = w & 1, wci = w >> 1;
  int nh = lane & 7, ml = lane >> 3;

  f32x4 acc[3][2][4];
  #pragma unroll
  for (int k = 0; k < 3; ++k)
    #pragma unroll
    for (int mt = 0; mt < 2; ++mt)
      #pragma unroll
      for (int ct = 0; ct < 4; ++ct) acc[k][mt][ct] = (f32x4){0.f, 0.f, 0.f, 0.f};

  for (int n0 = 0; n0 < N; n0 += 64) {
    #pragma unroll
    for (int it = 0; it < 6; ++it) {               // A: 3k x 64m x 64n
      int k = it >> 1, mh = it & 1;
      int m = mh * 32 + w * 8 + ml;
      *(uint4*)&A_l[(k * 64 + m) * 72 + nh * 8] =
          *(const uint4*)&Abf[((size_t)(k * Bc + bl) * N + m0 + m) * N + n0 + nh * 8];
    }
    #pragma unroll
    for (int it = 0; it < 4; ++it) {               // X: 128c x 64n
      int c = it * 32 + w * 8 + ml;
      *(uint4*)&X_l[c * 72 + nh * 8] =
          *(const uint4*)&xT[((size_t)bl * FT + c0 + c) * N + n0 + nh * 8];
    }
    __syncthreads();
    #pragma unroll
    for (int ks = 0; ks < 2; ++ks) {
      int nf = ks * 32 + quad * 8;
      short8 bfr[4];
      #pragma unroll
      for (int ct = 0; ct < 4; ++ct)
        bfr[ct] = *(const short8*)&X_l[(wci * 64 + ct * 16 + l15) * 72 + nf];
      #pragma unroll
      for (int k = 0; k < 3; ++k)
        #pragma unroll
        for (int mt = 0; mt < 2; ++mt) {
          short8 af = *(const short8*)&A_l[(k * 64 + wmi * 32 + mt * 16 + l15) * 72 + nf];
          #pragma unroll
          for (int ct = 0; ct < 4; ++ct)
            acc[k][mt][ct] = __builtin_amdgcn_mfma_f32_16x16x32_bf16(
                af, bfr[ct], acc[k][mt][ct], 0, 0, 0);
        }
    }
    __syncthreads();
  }
  #pragma unroll
  for (int k = 0; k < 3; ++k)
    #pragma unroll
    for (int mt = 0; mt < 2; ++mt)
      #pragma unroll
      for (int ct = 0; ct < 4; ++ct) {
        int col = c0 + wci * 64 + ct * 16 + l15;
        #pragma unroll
        for (int r = 0; r < 4; ++r) {
          int row = m0 + wmi * 32 + mt * 16 + quad * 4 + r;
          rk[k * kstride + ((size_t)bl * N + row) * FT + col] = acc[k][mt][ct][r];
        }
      }
}

// ---------------- fused theta + relu + conv + residual + relu + LN ----------
// block 256 = 4 waves = 4 rows; lane = o = ct. grid = Bc*N/4.
// Weights read directly from global wbf (48 KiB, L1/L2-resident, shared by all
// blocks) — LDS holds only the 4 staged rows => 36864 B => 4 blocks/CU.
__global__ __launch_bounds__(256, 4) void k_fuse(const float* rk, size_t kstride,
                                                 const float* x,
                                                 const unsigned short* wbf,
                                                 const float* tcb, const float* rcb,
                                                 const float* gam, const float* bet,
                                                 float* out, int b0) {
  __shared__ __align__(16) float row_l[4 * 2304];       // 36864 B (sg reuses)
  int tid = threadIdx.x;
  int w = tid >> 6, o = tid & 63;
  int r0l = blockIdx.x * 4;

  #pragma unroll
  for (int it = 0; it < 9; ++it) {       // rows: 2304 x 16B
    int ch = it * 256 + tid;
    int r = ch / 576, rem = ch % 576;
    int k = rem / 192, c4 = rem % 192;
    *(uint4*)&row_l[ch * 4] =
        *(const uint4*)&rk[(size_t)k * kstride + (size_t)(r0l + r) * FT + c4 * 4];
  }
  __syncthreads();

  const unsigned* thp = (const unsigned*)wbf;                          // kf pairs
  const unsigned long long* tcp = (const unsigned long long*)(wbf + 6144); // cc quads
  const unsigned* rcp = (const unsigned*)(wbf + 22528);                // f pairs

  // theta: sg[o][t] = relu(sum_kf rhs[m][kf*24+t] * Th[kf][o])
  float sg[T];
  #pragma unroll
  for (int t = 0; t < T; ++t) sg[t] = 0.f;
  const float* rw = &row_l[w * 2304];
  #pragma unroll 4
  for (int kf2 = 0; kf2 < 48; ++kf2) {
    unsigned u = thp[kf2 * 64 + o];
    float th0 = us2f((unsigned short)(u & 0xffffu));
    float th1 = us2f((unsigned short)(u >> 16));
    const float4* rp0 = (const float4*)&rw[(kf2 * 2) * 24];
    const float4* rp1 = (const float4*)&rw[(kf2 * 2 + 1) * 24];
    #pragma unroll
    for (int q = 0; q < 6; ++q) {
      float4 v0 = rp0[q], v1 = rp1[q];
      sg[q * 4 + 0] += th0 * v0.x + th1 * v1.x;
      sg[q * 4 + 1] += th0 * v0.y + th1 * v1.y;
      sg[q * 4 + 2] += th0 * v0.z + th1 * v1.z;
      sg[q * 4 + 3] += th0 * v0.w + th1 * v1.w;
    }
  }
  // per-wave private sg region (stride 28, 1792 floats <= 2304): no barrier
  // needed — wave only touches its own region.
  float* sgl = &row_l[w * 2304];
  #pragma unroll
  for (int q = 0; q < 6; ++q)
    ((float4*)&sgl[o * 28])[q] =
        make_float4(fmaxf(sg[q * 4], 0.f), fmaxf(sg[q * 4 + 1], 0.f),
                    fmaxf(sg[q * 4 + 2], 0.f), fmaxf(sg[q * 4 + 3], 0.f));

  // time conv (1,3) pad (0,1) + residual + relu + LN
  float acc[T];
  float bias = tcb[o] + rcb[o];
  #pragma unroll
  for (int t = 0; t < T; ++t) acc[t] = bias;

  #pragma unroll 4
  for (int cc = 0; cc < CC; ++cc) {
    unsigned long long wq = tcp[cc * 64 + o];
    float w0 = us2f((unsigned short)(wq & 0xffffu));
    float w1 = us2f((unsigned short)((wq >> 16) & 0xffffu));
    float w2 = us2f((unsigned short)((wq >> 32) & 0xffffu));
    const float4* sp = (const float4*)&sgl[cc * 28];   // wave-uniform broadcast
    float sv[T];
    #pragma unroll
    for (int q = 0; q < 6; ++q) {
      float4 v = sp[q];
      sv[q * 4 + 0] = v.x; sv[q * 4 + 1] = v.y;
      sv[q * 4 + 2] = v.z; sv[q * 4 + 3] = v.w;
    }
    acc[0] += w1 * sv[0] + w2 * sv[1];
    #pragma unroll
    for (int t = 1; t < T - 1; ++t)
      acc[t] += w0 * sv[t - 1] + w1 * sv[t] + w2 * sv[t + 1];
    acc[T - 1] += w0 * sv[T - 2] + w1 * sv[T - 1];
  }
  size_t grow = (size_t)b0 * N + r0l + w;
  const float* xrow = x + grow * FT;
  #pragma unroll 4
  for (int f2 = 0; f2 < 16; ++f2) {
    unsigned u = rcp[f2 * 64 + o];
    float wf0 = us2f((unsigned short)(u & 0xffffu));
    float wf1 = us2f((unsigned short)(u >> 16));
    const float4* xp0 = (const float4*)&xrow[(f2 * 2) * 24];     // wave-uniform
    const float4* xp1 = (const float4*)&xrow[(f2 * 2 + 1) * 24]; // broadcast
    #pragma unroll
    for (int q = 0; q < 6; ++q) {
      float4 v0 = xp0[q], v1 = xp1[q];
      acc[q * 4 + 0] += wf0 * v0.x + wf1 * v1.x;
      acc[q * 4 + 1] += wf0 * v0.y + wf1 * v1.y;
      acc[q * 4 + 2] += wf0 * v0.z + wf1 * v1.z;
      acc[q * 4 + 3] += wf0 * v0.w + wf1 * v1.w;
    }
  }
  float g = gam[o], be = bet[o];
  float ov[T];
  #pragma unroll
  for (int t = 0; t < T; ++t) {
    float z = fmaxf(acc[t], 0.f);
    float s = z, q = z * z;
    #pragma unroll
    for (int off = 1; off < 64; off <<= 1) {
      s += __shfl_xor(s, off);
      q += __shfl_xor(q, off);
    }
    float mu = s * (1.f / 64.f);
    float var = q * (1.f / 64.f) - mu * mu;
    ov[t] = (z - mu) * rsqrtf(var + 1e-5f) * g + be;
  }
  float* orow = out + grow * CTT + o * T;
  #pragma unroll
  for (int q = 0; q < 6; ++q)
    ((float4*)orow)[q] =
        make_float4(ov[q * 4], ov[q * 4 + 1], ov[q * 4 + 2], ov[q * 4 + 3]);
}

}  // namespace

extern "C" void kernel_launch(void* const* d_in, const int* in_sizes, int n_in,
                              void* d_out, int out_size, void* d_ws, size_t ws_size,
                              hipStream_t stream) {
  (void)in_sizes; (void)n_in; (void)out_size;
  const float* x     = (const float*)d_in[0];
  const float* W1    = (const float*)d_in[1];
  const float* W2    = (const float*)d_in[2];
  const float* W3    = (const float*)d_in[3];
  const float* U1    = (const float*)d_in[4];
  const float* U2    = (const float*)d_in[5];
  const float* U3    = (const float*)d_in[6];
  const float* cheb  = (const float*)d_in[7];
  const float* Theta = (const float*)d_in[8];
  const float* tcw   = (const float*)d_in[9];
  const float* tcb   = (const float*)d_in[10];
  const float* rcw   = (const float*)d_in[11];
  const float* rcb   = (const float*)d_in[12];
  const float* gam   = (const float*)d_in[13];
  const float* bet   = (const float*)d_in[14];
  float* out = (float*)d_out;

  // ---- runtime-adaptive workspace layout ----
  const size_t SB_BYTES = (size_t)B * N * N * 2;          // 33,554,432 (S bf16)
  const size_t WB_BYTES = 65536;                          // wbf (49152 used)
  const size_t AB_PER_B = (size_t)3 * N * N * 2;          // 6,291,456
  const size_t XT_PER_B = (size_t)FT * N * 2;             // 1,572,864
  const size_t RK_PER_B = (size_t)3 * N * FT * 4;         // 9,437,184
  const size_t SMALL = 2521472 * 4;                       // 10,085,888 B
  int Bc = 16;
  while (Bc > 1 && SB_BYTES + WB_BYTES + SMALL +
             (size_t)Bc * (AB_PER_B + XT_PER_B + RK_PER_B) > ws_size)
    Bc >>= 1;

  char* w = (char*)d_ws;
  __hip_bfloat16* Sb = (__hip_bfloat16*)w;
  unsigned short* wbf = (unsigned short*)(w + SB_BYTES);
  unsigned short* Abf = (unsigned short*)(w + SB_BYTES + WB_BYTES);
  unsigned short* xTb = (unsigned short*)(w + SB_BYTES + WB_BYTES +
                                          (size_t)Bc * AB_PER_B);
  float* rkbuf = (float*)(w + SB_BYTES + WB_BYTES +
                          (size_t)Bc * (AB_PER_B + XT_PER_B));
  size_t kstride = (size_t)Bc * N * FT;     // floats per k-bank of rk
  float* sm = (float*)(w + SB_BYTES + WB_BYTES +
                       (size_t)Bc * (AB_PER_B + XT_PER_B + RK_PER_B));
  float* lhst = sm;                       // B*T*F   = 12288
  float* lhs2 = lhst + B * T * F;         // B*T*N   = 393216
  float* rhst = lhs2 + B * T * N;         // B*N*T   = 393216
  float* w3x  = rhst + B * N * T;         // B*N*T   = 393216
  float* Elog = w3x + B * N * T;          // B*T*T   = 9216
  float* E    = Elog + B * T * T;         // B*T*T   = 9216
  float* EW1  = E + B * T * T;            // B*T     = 384
  float* tmp1 = EW1 + B * T;              // B*N*F   = 524288
  float* lhss = tmp1 + B * N * F;         // B*N*T   = 393216
  float* rhss = lhss + B * N * T;         // B*N*T   = 393216

  // temporal attention
  k_lhs_t<<<B * T * F, 64, 0, stream>>>(x, U1, lhst);
  k_lhs2<<<(B * T * N) / 256, 256, 0, stream>>>(lhst, U2, lhs2);
  k_fx<<<(B * N * T) / 256, 256, 0, stream>>>(x, U3, W3, rhst, w3x);
  k_Elog<<<B * T * T, 64, 0, stream>>>(lhs2, rhst, Elog);
  k_Esm<<<B, 64, 0, stream>>>(Elog, E);
  k_EW1<<<B, 64, 0, stream>>>(E, W1, EW1);

  // spatial attention (x_TAt folded out)
  k_tmp1x<<<(B * N * F) / 256, 256, 0, stream>>>(x, EW1, tmp1);
  k_lhs_s<<<(B * N * T) / 256, 256, 0, stream>>>(tmp1, W2, lhss);
  k_rhss<<<(B * N * T) / 256, 256, 0, stream>>>(w3x, E, rhss);
  k_Slog<<<dim3(N / 256, N / 16, B), 256, 0, stream>>>(lhss, rhss, Sb);
  k_Ssm3<<<dim3(N / 256, B), 256, 0, stream>>>(Sb);

  // weight prep (once)
  k_prepW<<<1, 256, 0, stream>>>(Theta, tcw, rcw, wbf);

  // per-chunk: operand prep + fused GEMM + fused epilogue
  for (int b0 = 0; b0 < B; b0 += Bc) {
    k_prepA<<<dim3(N / 64, N / 64, 3 * Bc), 256, 0, stream>>>(cheb, Sb, Abf, Bc, b0);
    k_prepX<<<dim3(N / 64, FT / 64, Bc), 256, 0, stream>>>(x, xTb, b0);
    k_gemm3<<<dim3(FT / 128, N / 64, Bc), 256, 0, stream>>>(Abf, xTb, rkbuf,
                                                            kstride, Bc);
    k_fuse<<<Bc * N / 4, 256, 0, stream>>>(rkbuf, kstride, x, wbf, tcb, rcb,
                                           gam, bet, out, b0);
  }
}

// Round 2
// 1320.097 us; speedup vs baseline: 1.0342x; 1.0342x over previous
//
#include <hip/hip_runtime.h>
#include <hip/hip_bf16.h>
#include <math.h>

// ASTGCN block, MI355X. Round 8: keep k_fuse weights-in-global (LDS 36864 =>
// 4 blocks/CU) but drop the min-waves launch-bound that strangled VGPRs to 56
// (killed load pipelining, r7 regression 379->451us). Plain
// __launch_bounds__(256) compiles this shape to ~124 VGPR (r6 evidence) which
// natively allows 4 waves/SIMD = the same 4 blocks/CU, WITH full ILP.

namespace {

constexpr int B = 16, N = 1024, F = 32, T = 24, CC = 64, CT = 64;
constexpr int FT = F * T;     // 768
constexpr int CTT = CT * T;   // 1536

using f32x4  = __attribute__((ext_vector_type(4))) float;
using short8 = __attribute__((ext_vector_type(8))) short;

__device__ __forceinline__ float b2f(__hip_bfloat16 v) { return __bfloat162float(v); }
__device__ __forceinline__ unsigned short f2bu(float x) {   // fp32 -> bf16 bits, RNE
  union { float f; unsigned u; } c; c.f = x;
  unsigned u = c.u;
  return (unsigned short)((u + 0x7FFFu + ((u >> 16) & 1u)) >> 16);
}
__device__ __forceinline__ float us2f(unsigned short u) {   // bf16 bits -> fp32
  union { unsigned u; float f; } c; c.u = ((unsigned)u) << 16; return c.f;
}

// ---------------- temporal attention ----------------
__global__ void k_lhs_t(const float* x, const float* U1, float* lhst) {
  int bi = blockIdx.x;                 // (b*T+t)*F + f
  int f = bi % F; int t = (bi / F) % T; int b = bi / (F * T);
  int tid = threadIdx.x;
  float acc = 0.f;
  for (int n = tid; n < N; n += 64)
    acc += x[(((size_t)b * N + n) * F + f) * T + t] * U1[n];
  #pragma unroll
  for (int off = 32; off > 0; off >>= 1) acc += __shfl_down(acc, off);
  if (tid == 0) lhst[bi] = acc;
}

__global__ void k_lhs2(const float* lhst, const float* U2, float* lhs2) {
  __shared__ float ls[F];
  int tid = threadIdx.x;
  int id = blockIdx.x * 256 + tid;   // (b*T+t)*N + n
  int n = id % N; int bt = id / N;
  if (tid < F) ls[tid] = lhst[bt * F + tid];
  __syncthreads();
  float acc = 0.f;
  #pragma unroll
  for (int f = 0; f < F; ++f) acc += ls[f] * U2[f * N + n];
  lhs2[id] = acc;
}

__global__ void k_fx(const float* x, const float* U3, const float* W3,
                     float* rhst, float* w3x) {
  __shared__ float u3s[F], w3s[F];
  int tid = threadIdx.x;
  if (tid < F) { u3s[tid] = U3[tid]; w3s[tid] = W3[tid]; }
  __syncthreads();
  int id = blockIdx.x * 256 + tid;     // (b*N+n)*T + t
  int t = id % T; int bn = id / T;
  float au = 0.f, aw = 0.f;
  #pragma unroll
  for (int f = 0; f < F; ++f) {
    float v = x[((size_t)bn * F + f) * T + t];
    au += u3s[f] * v; aw += w3s[f] * v;
  }
  rhst[id] = au; w3x[id] = aw;
}

__global__ void k_Elog(const float* lhs2, const float* rhst, float* Elog) {
  int bi = blockIdx.x;                 // (b*T+t)*T + s
  int s = bi % T; int t = (bi / T) % T; int b = bi / (T * T);
  int tid = threadIdx.x;
  float acc = 0.f;
  for (int n = tid; n < N; n += 64)
    acc += lhs2[(b * T + t) * N + n] * rhst[(b * N + n) * T + s];
  #pragma unroll
  for (int off = 32; off > 0; off >>= 1) acc += __shfl_down(acc, off);
  if (tid == 0) Elog[bi] = acc;
}

__global__ void k_Esm(const float* Elog, float* E) {
  int b = blockIdx.x; int s = threadIdx.x;
  if (s >= T) return;
  float mx = -1e30f;
  for (int t = 0; t < T; ++t) mx = fmaxf(mx, Elog[(b * T + t) * T + s]);
  float sum = 0.f;
  for (int t = 0; t < T; ++t) sum += expf(Elog[(b * T + t) * T + s] - mx);
  float inv = 1.f / sum;
  for (int t = 0; t < T; ++t)
    E[(b * T + t) * T + s] = expf(Elog[(b * T + t) * T + s] - mx) * inv;
}

__global__ void k_EW1(const float* E, const float* W1, float* EW1) {
  int b = blockIdx.x; int t = threadIdx.x;
  if (t >= T) return;
  float acc = 0.f;
  for (int s = 0; s < T; ++s) acc += E[(b * T + t) * T + s] * W1[s];
  EW1[b * T + t] = acc;
}

// ---------------- spatial attention ----------------
__global__ void k_tmp1x(const float* x, const float* EW1, float* tmp1) {
  __shared__ float ew[T];
  int tid = threadIdx.x;
  int id = blockIdx.x * 256 + tid;       // (b*N+n)*F + f
  int b = id / (N * F);
  if (tid < T) ew[tid] = EW1[b * T + tid];
  __syncthreads();
  const float* xr = x + (size_t)id * T;
  float acc = 0.f;
  #pragma unroll
  for (int t = 0; t < T; ++t) acc += xr[t] * ew[t];
  tmp1[id] = acc;
}

__global__ void k_lhs_s(const float* tmp1, const float* W2, float* lhss) {
  int id = blockIdx.x * 256 + threadIdx.x;
  int t = id % T; int bn = id / T;
  float acc = 0.f;
  #pragma unroll
  for (int f = 0; f < F; ++f) acc += tmp1[bn * F + f] * W2[f * T + t];
  lhss[id] = acc;
}

__global__ void k_rhss(const float* w3x, const float* E, float* rhss) {
  __shared__ float Ec[T];
  int tid = threadIdx.x;
  int id = blockIdx.x * 256 + tid;       // (b*T+t)*N + m
  int m = id % N; int t = (id / N) % T; int b = id / (N * T);
  if (tid < T) Ec[tid] = E[(b * T + tid) * T + t];
  __syncthreads();
  const float* wr = w3x + ((size_t)b * N + m) * T;
  float acc = 0.f;
  #pragma unroll
  for (int tp = 0; tp < T; ++tp) acc += wr[tp] * Ec[tp];
  rhss[id] = acc;
}

__global__ void k_Slog(const float* lhss, const float* rhss, __hip_bfloat16* S) {
  __shared__ float rt[T][256];
  __shared__ float lt[16][T];
  int m0 = blockIdx.x * 256, n0 = blockIdx.y * 16, b = blockIdx.z;
  int tid = threadIdx.x;
  for (int t = 0; t < T; ++t) rt[t][tid] = rhss[((size_t)b * T + t) * N + m0 + tid];
  for (int i = tid; i < 16 * T; i += 256) {
    int n = i / T, t = i % T;
    lt[n][t] = lhss[((size_t)b * N + n0 + n) * T + t];
  }
  __syncthreads();
  #pragma unroll 4
  for (int n = 0; n < 16; ++n) {
    float acc = 0.f;
    #pragma unroll
    for (int t = 0; t < T; ++t) acc += lt[n][t] * rt[t][tid];
    S[((size_t)b * N + n0 + n) * N + m0 + tid] = __float2bfloat16(acc);
  }
}

__global__ void k_Ssm3(__hip_bfloat16* S) {
  int m = blockIdx.x * 256 + threadIdx.x; int b = blockIdx.y;
  size_t base = (size_t)b * N * N + m;
  float mx = -1e30f;
  for (int n = 0; n < N; ++n) mx = fmaxf(mx, b2f(S[base + (size_t)n * N]));
  float sum = 0.f;
  for (int n = 0; n < N; ++n) sum += expf(b2f(S[base + (size_t)n * N]) - mx);
  float inv = 1.f / sum;
  for (int n = 0; n < N; ++n) {
    size_t i = base + (size_t)n * N;
    S[i] = __float2bfloat16(expf(b2f(S[i]) - mx) * inv);
  }
}

// ---------------- GEMM operand prep (transpose to n-contiguous bf16) --------
// Abf[(k*Bc+bl)][m][n] = bf16(cheb[k,n,m] * S[b,n,m]); grid (N/64, N/64, 3*Bc)
__global__ __launch_bounds__(256) void k_prepA(const float* cheb,
                                               const __hip_bfloat16* S,
                                               unsigned short* Abf,
                                               int Bc, int b0) {
  __shared__ float Tl[64][65];
  int z = blockIdx.z;
  int k = z / Bc, bl = z % Bc, b = b0 + bl;
  int n0 = blockIdx.x * 64, m0 = blockIdx.y * 64;
  int tid = threadIdx.x;
  int j = tid & 63, i4 = tid >> 6;
  #pragma unroll
  for (int it = 0; it < 16; ++it) {
    int i = it * 4 + i4;
    Tl[i][j] = cheb[((size_t)k * N + n0 + i) * N + m0 + j] *
               b2f(S[((size_t)b * N + n0 + i) * N + m0 + j]);
  }
  __syncthreads();
  int i2 = (tid & 31) * 2, j8 = tid >> 5;
  #pragma unroll
  for (int it = 0; it < 8; ++it) {
    int jj = it * 8 + j8;
    unsigned u = (unsigned)f2bu(Tl[i2][jj]) | ((unsigned)f2bu(Tl[i2 + 1][jj]) << 16);
    *(unsigned*)&Abf[((size_t)z * N + m0 + jj) * N + n0 + i2] = u;
  }
}

// xT[bl][c][n] = bf16(x[b,n,c]); grid (N/64, FT/64=12, Bc)
__global__ __launch_bounds__(256) void k_prepX(const float* x, unsigned short* xT,
                                               int b0) {
  __shared__ float Tl[64][65];
  int bl = blockIdx.z, b = b0 + bl;
  int n0 = blockIdx.x * 64, c0 = blockIdx.y * 64;
  int tid = threadIdx.x;
  int j = tid & 63, i4 = tid >> 6;
  #pragma unroll
  for (int it = 0; it < 16; ++it) {
    int i = it * 4 + i4;
    Tl[i][j] = x[((size_t)b * N + n0 + i) * FT + c0 + j];
  }
  __syncthreads();
  int i2 = (tid & 31) * 2, j8 = tid >> 5;
  #pragma unroll
  for (int it = 0; it < 8; ++it) {
    int jj = it * 8 + j8;
    unsigned u = (unsigned)f2bu(Tl[i2][jj]) | ((unsigned)f2bu(Tl[i2 + 1][jj]) << 16);
    *(unsigned*)&xT[((size_t)bl * FT + c0 + jj) * N + n0 + i2] = u;
  }
}

// weights -> bf16, packed for direct (non-LDS) coalesced reads in k_fuse.
// Layout (ushort indices):
//   Theta pairs : [(kf>>1)*128 + o*2 + (kf&1)]          0     .. 6143
//   tconv quads : [6144 + (cc*64 + o)*4 + j] (j=3 pad)  6144  .. 22527
//   rconv pairs : [22528 + (f>>1)*128 + o*2 + (f&1)]    22528 .. 24575
__global__ void k_prepW(const float* Theta, const float* tcw, const float* rcw,
                        unsigned short* wbf) {
  int tid = threadIdx.x;
  for (int g = tid; g < 96 * 64; g += 256) {
    int kf = g >> 6, o = g & 63;
    wbf[(kf >> 1) * 128 + o * 2 + (kf & 1)] = f2bu(Theta[g]);
  }
  for (int g = tid; g < 64 * 64 * 4; g += 256) {
    int cc = g >> 8, o = (g >> 2) & 63, j = g & 3;
    wbf[6144 + g] = (j < 3) ? f2bu(tcw[o * 192 + cc * 3 + j]) : (unsigned short)0;
  }
  for (int g = tid; g < 32 * 64; g += 256) {
    int f = g >> 6, o = g & 63;
    wbf[22528 + (f >> 1) * 128 + o * 2 + (f & 1)] = f2bu(rcw[o * 32 + f]);
  }
}

// ---------------- Chebyshev contraction: fused 3-k MFMA bf16 v2 -------------
// Both operands bf16, n-contiguous. Staging = pure 16B copies.
// Tile 64m x 128c x 64n; waves 2x2 (32m x 64c each). grid (6, 16, Bc).
__global__ __launch_bounds__(256) void k_gemm3(const unsigned short* Abf,
                                               const unsigned short* xT,
                                               float* rk, size_t kstride,
                                               int Bc) {
  __shared__ __align__(16) unsigned short A_l[3 * 64 * 72];   // 27648 B
  __shared__ __align__(16) unsigned short X_l[128 * 72];      // 18432 B
  int bl = blockIdx.z;
  int m0 = blockIdx.y * 64, c0 = blockIdx.x * 128;
  int tid = threadIdx.x;
  int lane = tid & 63, w = tid >> 6;
  int l15 = lane & 15, quad = lane >> 4;
  int wmi = w & 1, wci = w >> 1;
  int nh = lane & 7, ml = lane >> 3;

  f32x4 acc[3][2][4];
  #pragma unroll
  for (int k = 0; k < 3; ++k)
    #pragma unroll
    for (int mt = 0; mt < 2; ++mt)
      #pragma unroll
      for (int ct = 0; ct < 4; ++ct) acc[k][mt][ct] = (f32x4){0.f, 0.f, 0.f, 0.f};

  for (int n0 = 0; n0 < N; n0 += 64) {
    #pragma unroll
    for (int it = 0; it < 6; ++it) {               // A: 3k x 64m x 64n
      int k = it >> 1, mh = it & 1;
      int m = mh * 32 + w * 8 + ml;
      *(uint4*)&A_l[(k * 64 + m) * 72 + nh * 8] =
          *(const uint4*)&Abf[((size_t)(k * Bc + bl) * N + m0 + m) * N + n0 + nh * 8];
    }
    #pragma unroll
    for (int it = 0; it < 4; ++it) {               // X: 128c x 64n
      int c = it * 32 + w * 8 + ml;
      *(uint4*)&X_l[c * 72 + nh * 8] =
          *(const uint4*)&xT[((size_t)bl * FT + c0 + c) * N + n0 + nh * 8];
    }
    __syncthreads();
    #pragma unroll
    for (int ks = 0; ks < 2; ++ks) {
      int nf = ks * 32 + quad * 8;
      short8 bfr[4];
      #pragma unroll
      for (int ct = 0; ct < 4; ++ct)
        bfr[ct] = *(const short8*)&X_l[(wci * 64 + ct * 16 + l15) * 72 + nf];
      #pragma unroll
      for (int k = 0; k < 3; ++k)
        #pragma unroll
        for (int mt = 0; mt < 2; ++mt) {
          short8 af = *(const short8*)&A_l[(k * 64 + wmi * 32 + mt * 16 + l15) * 72 + nf];
          #pragma unroll
          for (int ct = 0; ct < 4; ++ct)
            acc[k][mt][ct] = __builtin_amdgcn_mfma_f32_16x16x32_bf16(
                af, bfr[ct], acc[k][mt][ct], 0, 0, 0);
        }
    }
    __syncthreads();
  }
  #pragma unroll
  for (int k = 0; k < 3; ++k)
    #pragma unroll
    for (int mt = 0; mt < 2; ++mt)
      #pragma unroll
      for (int ct = 0; ct < 4; ++ct) {
        int col = c0 + wci * 64 + ct * 16 + l15;
        #pragma unroll
        for (int r = 0; r < 4; ++r) {
          int row = m0 + wmi * 32 + mt * 16 + quad * 4 + r;
          rk[k * kstride + ((size_t)bl * N + row) * FT + col] = acc[k][mt][ct][r];
        }
      }
}

// ---------------- fused theta + relu + conv + residual + relu + LN ----------
// block 256 = 4 waves = 4 rows; lane = o = ct. grid = Bc*N/4.
// Weights read directly from global wbf (48 KiB, L2-resident, shared by all
// blocks) — LDS holds only the 4 staged rows => 36864 B => 4 blocks/CU.
// Plain launch bounds: compiler needs ~124 VGPR here to pipeline the weight
// loads; (256,4) forced 56 VGPR and serialized them (r7: 451us vs r6 379us).
__global__ __launch_bounds__(256) void k_fuse(const float* rk, size_t kstride,
                                              const float* x,
                                              const unsigned short* wbf,
                                              const float* tcb, const float* rcb,
                                              const float* gam, const float* bet,
                                              float* out, int b0) {
  __shared__ __align__(16) float row_l[4 * 2304];       // 36864 B (sg reuses)
  int tid = threadIdx.x;
  int w = tid >> 6, o = tid & 63;
  int r0l = blockIdx.x * 4;

  #pragma unroll
  for (int it = 0; it < 9; ++it) {       // rows: 2304 x 16B
    int ch = it * 256 + tid;
    int r = ch / 576, rem = ch % 576;
    int k = rem / 192, c4 = rem % 192;
    *(uint4*)&row_l[ch * 4] =
        *(const uint4*)&rk[(size_t)k * kstride + (size_t)(r0l + r) * FT + c4 * 4];
  }
  __syncthreads();

  const unsigned* thp = (const unsigned*)wbf;                          // kf pairs
  const unsigned long long* tcp = (const unsigned long long*)(wbf + 6144); // cc quads
  const unsigned* rcp = (const unsigned*)(wbf + 22528);                // f pairs

  // theta: sg[o][t] = relu(sum_kf rhs[m][kf*24+t] * Th[kf][o])
  float sg[T];
  #pragma unroll
  for (int t = 0; t < T; ++t) sg[t] = 0.f;
  const float* rw = &row_l[w * 2304];
  #pragma unroll 4
  for (int kf2 = 0; kf2 < 48; ++kf2) {
    unsigned u = thp[kf2 * 64 + o];
    float th0 = us2f((unsigned short)(u & 0xffffu));
    float th1 = us2f((unsigned short)(u >> 16));
    const float4* rp0 = (const float4*)&rw[(kf2 * 2) * 24];
    const float4* rp1 = (const float4*)&rw[(kf2 * 2 + 1) * 24];
    #pragma unroll
    for (int q = 0; q < 6; ++q) {
      float4 v0 = rp0[q], v1 = rp1[q];
      sg[q * 4 + 0] += th0 * v0.x + th1 * v1.x;
      sg[q * 4 + 1] += th0 * v0.y + th1 * v1.y;
      sg[q * 4 + 2] += th0 * v0.z + th1 * v1.z;
      sg[q * 4 + 3] += th0 * v0.w + th1 * v1.w;
    }
  }
  // per-wave private sg region (stride 28, 1792 floats <= 2304): no barrier
  // needed — wave only touches its own region.
  float* sgl = &row_l[w * 2304];
  #pragma unroll
  for (int q = 0; q < 6; ++q)
    ((float4*)&sgl[o * 28])[q] =
        make_float4(fmaxf(sg[q * 4], 0.f), fmaxf(sg[q * 4 + 1], 0.f),
                    fmaxf(sg[q * 4 + 2], 0.f), fmaxf(sg[q * 4 + 3], 0.f));

  // time conv (1,3) pad (0,1) + residual + relu + LN
  float acc[T];
  float bias = tcb[o] + rcb[o];
  #pragma unroll
  for (int t = 0; t < T; ++t) acc[t] = bias;

  #pragma unroll 4
  for (int cc = 0; cc < CC; ++cc) {
    unsigned long long wq = tcp[cc * 64 + o];
    float w0 = us2f((unsigned short)(wq & 0xffffu));
    float w1 = us2f((unsigned short)((wq >> 16) & 0xffffu));
    float w2 = us2f((unsigned short)((wq >> 32) & 0xffffu));
    const float4* sp = (const float4*)&sgl[cc * 28];   // wave-uniform broadcast
    float sv[T];
    #pragma unroll
    for (int q = 0; q < 6; ++q) {
      float4 v = sp[q];
      sv[q * 4 + 0] = v.x; sv[q * 4 + 1] = v.y;
      sv[q * 4 + 2] = v.z; sv[q * 4 + 3] = v.w;
    }
    acc[0] += w1 * sv[0] + w2 * sv[1];
    #pragma unroll
    for (int t = 1; t < T - 1; ++t)
      acc[t] += w0 * sv[t - 1] + w1 * sv[t] + w2 * sv[t + 1];
    acc[T - 1] += w0 * sv[T - 2] + w1 * sv[T - 1];
  }
  size_t grow = (size_t)b0 * N + r0l + w;
  const float* xrow = x + grow * FT;
  #pragma unroll 4
  for (int f2 = 0; f2 < 16; ++f2) {
    unsigned u = rcp[f2 * 64 + o];
    float wf0 = us2f((unsigned short)(u & 0xffffu));
    float wf1 = us2f((unsigned short)(u >> 16));
    const float4* xp0 = (const float4*)&xrow[(f2 * 2) * 24];     // wave-uniform
    const float4* xp1 = (const float4*)&xrow[(f2 * 2 + 1) * 24]; // broadcast
    #pragma unroll
    for (int q = 0; q < 6; ++q) {
      float4 v0 = xp0[q], v1 = xp1[q];
      acc[q * 4 + 0] += wf0 * v0.x + wf1 * v1.x;
      acc[q * 4 + 1] += wf0 * v0.y + wf1 * v1.y;
      acc[q * 4 + 2] += wf0 * v0.z + wf1 * v1.z;
      acc[q * 4 + 3] += wf0 * v0.w + wf1 * v1.w;
    }
  }
  float g = gam[o], be = bet[o];
  float ov[T];
  #pragma unroll
  for (int t = 0; t < T; ++t) {
    float z = fmaxf(acc[t], 0.f);
    float s = z, q = z * z;
    #pragma unroll
    for (int off = 1; off < 64; off <<= 1) {
      s += __shfl_xor(s, off);
      q += __shfl_xor(q, off);
    }
    float mu = s * (1.f / 64.f);
    float var = q * (1.f / 64.f) - mu * mu;
    ov[t] = (z - mu) * rsqrtf(var + 1e-5f) * g + be;
  }
  float* orow = out + grow * CTT + o * T;
  #pragma unroll
  for (int q = 0; q < 6; ++q)
    ((float4*)orow)[q] =
        make_float4(ov[q * 4], ov[q * 4 + 1], ov[q * 4 + 2], ov[q * 4 + 3]);
}

}  // namespace

extern "C" void kernel_launch(void* const* d_in, const int* in_sizes, int n_in,
                              void* d_out, int out_size, void* d_ws, size_t ws_size,
                              hipStream_t stream) {
  (void)in_sizes; (void)n_in; (void)out_size;
  const float* x     = (const float*)d_in[0];
  const float* W1    = (const float*)d_in[1];
  const float* W2    = (const float*)d_in[2];
  const float* W3    = (const float*)d_in[3];
  const float* U1    = (const float*)d_in[4];
  const float* U2    = (const float*)d_in[5];
  const float* U3    = (const float*)d_in[6];
  const float* cheb  = (const float*)d_in[7];
  const float* Theta = (const float*)d_in[8];
  const float* tcw   = (const float*)d_in[9];
  const float* tcb   = (const float*)d_in[10];
  const float* rcw   = (const float*)d_in[11];
  const float* rcb   = (const float*)d_in[12];
  const float* gam   = (const float*)d_in[13];
  const float* bet   = (const float*)d_in[14];
  float* out = (float*)d_out;

  // ---- runtime-adaptive workspace layout ----
  const size_t SB_BYTES = (size_t)B * N * N * 2;          // 33,554,432 (S bf16)
  const size_t WB_BYTES = 65536;                          // wbf (49152 used)
  const size_t AB_PER_B = (size_t)3 * N * N * 2;          // 6,291,456
  const size_t XT_PER_B = (size_t)FT * N * 2;             // 1,572,864
  const size_t RK_PER_B = (size_t)3 * N * FT * 4;         // 9,437,184
  const size_t SMALL = 2521472 * 4;                       // 10,085,888 B
  int Bc = 16;
  while (Bc > 1 && SB_BYTES + WB_BYTES + SMALL +
             (size_t)Bc * (AB_PER_B + XT_PER_B + RK_PER_B) > ws_size)
    Bc >>= 1;

  char* w = (char*)d_ws;
  __hip_bfloat16* Sb = (__hip_bfloat16*)w;
  unsigned short* wbf = (unsigned short*)(w + SB_BYTES);
  unsigned short* Abf = (unsigned short*)(w + SB_BYTES + WB_BYTES);
  unsigned short* xTb = (unsigned short*)(w + SB_BYTES + WB_BYTES +
                                          (size_t)Bc * AB_PER_B);
  float* rkbuf = (float*)(w + SB_BYTES + WB_BYTES +
                          (size_t)Bc * (AB_PER_B + XT_PER_B));
  size_t kstride = (size_t)Bc * N * FT;     // floats per k-bank of rk
  float* sm = (float*)(w + SB_BYTES + WB_BYTES +
                       (size_t)Bc * (AB_PER_B + XT_PER_B + RK_PER_B));
  float* lhst = sm;                       // B*T*F   = 12288
  float* lhs2 = lhst + B * T * F;         // B*T*N   = 393216
  float* rhst = lhs2 + B * T * N;         // B*N*T   = 393216
  float* w3x  = rhst + B * N * T;         // B*N*T   = 393216
  float* Elog = w3x + B * N * T;          // B*T*T   = 9216
  float* E    = Elog + B * T * T;         // B*T*T   = 9216
  float* EW1  = E + B * T * T;            // B*T     = 384
  float* tmp1 = EW1 + B * T;              // B*N*F   = 524288
  float* lhss = tmp1 + B * N * F;         // B*N*T   = 393216
  float* rhss = lhss + B * N * T;         // B*N*T   = 393216

  // temporal attention
  k_lhs_t<<<B * T * F, 64, 0, stream>>>(x, U1, lhst);
  k_lhs2<<<(B * T * N) / 256, 256, 0, stream>>>(lhst, U2, lhs2);
  k_fx<<<(B * N * T) / 256, 256, 0, stream>>>(x, U3, W3, rhst, w3x);
  k_Elog<<<B * T * T, 64, 0, stream>>>(lhs2, rhst, Elog);
  k_Esm<<<B, 64, 0, stream>>>(Elog, E);
  k_EW1<<<B, 64, 0, stream>>>(E, W1, EW1);

  // spatial attention (x_TAt folded out)
  k_tmp1x<<<(B * N * F) / 256, 256, 0, stream>>>(x, EW1, tmp1);
  k_lhs_s<<<(B * N * T) / 256, 256, 0, stream>>>(tmp1, W2, lhss);
  k_rhss<<<(B * N * T) / 256, 256, 0, stream>>>(w3x, E, rhss);
  k_Slog<<<dim3(N / 256, N / 16, B), 256, 0, stream>>>(lhss, rhss, Sb);
  k_Ssm3<<<dim3(N / 256, B), 256, 0, stream>>>(Sb);

  // weight prep (once)
  k_prepW<<<1, 256, 0, stream>>>(Theta, tcw, rcw, wbf);

  // per-chunk: operand prep + fused GEMM + fused epilogue
  for (int b0 = 0; b0 < B; b0 += Bc) {
    k_prepA<<<dim3(N / 64, N / 64, 3 * Bc), 256, 0, stream>>>(cheb, Sb, Abf, Bc, b0);
    k_prepX<<<dim3(N / 64, FT / 64, Bc), 256, 0, stream>>>(x, xTb, b0);
    k_gemm3<<<dim3(FT / 128, N / 64, Bc), 256, 0, stream>>>(Abf, xTb, rkbuf,
                                                            kstride, Bc);
    k_fuse<<<Bc * N / 4, 256, 0, stream>>>(rkbuf, kstride, x, wbf, tcb, rcb,
                                           gam, bet, out, b0);
  }
}

// Round 3
// 1113.168 us; speedup vs baseline: 1.2264x; 1.1859x over previous
//
#include <hip/hip_runtime.h>
#include <hip/hip_bf16.h>
#include <math.h>

// ASTGCN block, MI355X. Round 9: k_fuse rebuilt on MFMA. Theta (M=96,K=96,
// N=64) and time-conv (M=96,K=192 im2col) run on the matrix pipe; residual +
// LN stay fp32 VALU. k_prepX emits c' = t*32+f so k_gemm3 (unchanged) writes
// rk kf-contiguous per (m,t). k_prepW emits ThB[o][kf], tcwB[o][j*64+cc],
// rcw pairs. sg in LDS bf16 XOR-swizzled ((row&7)<<4) to kill the 16-way
// conflict of a 128B-stride row. LDS union 38272 B -> 4 blocks/CU.

namespace {

constexpr int B = 16, N = 1024, F = 32, T = 24, CC = 64, CT = 64;
constexpr int FT = F * T;     // 768
constexpr int CTT = CT * T;   // 1536

using f32x4  = __attribute__((ext_vector_type(4))) float;
using short8 = __attribute__((ext_vector_type(8))) short;

__device__ __forceinline__ float b2f(__hip_bfloat16 v) { return __bfloat162float(v); }
__device__ __forceinline__ unsigned short f2bu(float x) {   // fp32 -> bf16 bits, RNE
  union { float f; unsigned u; } c; c.f = x;
  unsigned u = c.u;
  return (unsigned short)((u + 0x7FFFu + ((u >> 16) & 1u)) >> 16);
}
__device__ __forceinline__ float us2f(unsigned short u) {   // bf16 bits -> fp32
  union { unsigned u; float f; } c; c.u = ((unsigned)u) << 16; return c.f;
}

// ---------------- temporal attention ----------------
__global__ void k_lhs_t(const float* x, const float* U1, float* lhst) {
  int bi = blockIdx.x;                 // (b*T+t)*F + f
  int f = bi % F; int t = (bi / F) % T; int b = bi / (F * T);
  int tid = threadIdx.x;
  float acc = 0.f;
  for (int n = tid; n < N; n += 64)
    acc += x[(((size_t)b * N + n) * F + f) * T + t] * U1[n];
  #pragma unroll
  for (int off = 32; off > 0; off >>= 1) acc += __shfl_down(acc, off);
  if (tid == 0) lhst[bi] = acc;
}

__global__ void k_lhs2(const float* lhst, const float* U2, float* lhs2) {
  __shared__ float ls[F];
  int tid = threadIdx.x;
  int id = blockIdx.x * 256 + tid;   // (b*T+t)*N + n
  int n = id % N; int bt = id / N;
  if (tid < F) ls[tid] = lhst[bt * F + tid];
  __syncthreads();
  float acc = 0.f;
  #pragma unroll
  for (int f = 0; f < F; ++f) acc += ls[f] * U2[f * N + n];
  lhs2[id] = acc;
}

__global__ void k_fx(const float* x, const float* U3, const float* W3,
                     float* rhst, float* w3x) {
  __shared__ float u3s[F], w3s[F];
  int tid = threadIdx.x;
  if (tid < F) { u3s[tid] = U3[tid]; w3s[tid] = W3[tid]; }
  __syncthreads();
  int id = blockIdx.x * 256 + tid;     // (b*N+n)*T + t
  int t = id % T; int bn = id / T;
  float au = 0.f, aw = 0.f;
  #pragma unroll
  for (int f = 0; f < F; ++f) {
    float v = x[((size_t)bn * F + f) * T + t];
    au += u3s[f] * v; aw += w3s[f] * v;
  }
  rhst[id] = au; w3x[id] = aw;
}

__global__ void k_Elog(const float* lhs2, const float* rhst, float* Elog) {
  int bi = blockIdx.x;                 // (b*T+t)*T + s
  int s = bi % T; int t = (bi / T) % T; int b = bi / (T * T);
  int tid = threadIdx.x;
  float acc = 0.f;
  for (int n = tid; n < N; n += 64)
    acc += lhs2[(b * T + t) * N + n] * rhst[(b * N + n) * T + s];
  #pragma unroll
  for (int off = 32; off > 0; off >>= 1) acc += __shfl_down(acc, off);
  if (tid == 0) Elog[bi] = acc;
}

__global__ void k_Esm(const float* Elog, float* E) {
  int b = blockIdx.x; int s = threadIdx.x;
  if (s >= T) return;
  float mx = -1e30f;
  for (int t = 0; t < T; ++t) mx = fmaxf(mx, Elog[(b * T + t) * T + s]);
  float sum = 0.f;
  for (int t = 0; t < T; ++t) sum += expf(Elog[(b * T + t) * T + s] - mx);
  float inv = 1.f / sum;
  for (int t = 0; t < T; ++t)
    E[(b * T + t) * T + s] = expf(Elog[(b * T + t) * T + s] - mx) * inv;
}

__global__ void k_EW1(const float* E, const float* W1, float* EW1) {
  int b = blockIdx.x; int t = threadIdx.x;
  if (t >= T) return;
  float acc = 0.f;
  for (int s = 0; s < T; ++s) acc += E[(b * T + t) * T + s] * W1[s];
  EW1[b * T + t] = acc;
}

// ---------------- spatial attention ----------------
__global__ void k_tmp1x(const float* x, const float* EW1, float* tmp1) {
  __shared__ float ew[T];
  int tid = threadIdx.x;
  int id = blockIdx.x * 256 + tid;       // (b*N+n)*F + f
  int b = id / (N * F);
  if (tid < T) ew[tid] = EW1[b * T + tid];
  __syncthreads();
  const float* xr = x + (size_t)id * T;
  float acc = 0.f;
  #pragma unroll
  for (int t = 0; t < T; ++t) acc += xr[t] * ew[t];
  tmp1[id] = acc;
}

__global__ void k_lhs_s(const float* tmp1, const float* W2, float* lhss) {
  int id = blockIdx.x * 256 + threadIdx.x;
  int t = id % T; int bn = id / T;
  float acc = 0.f;
  #pragma unroll
  for (int f = 0; f < F; ++f) acc += tmp1[bn * F + f] * W2[f * T + t];
  lhss[id] = acc;
}

__global__ void k_rhss(const float* w3x, const float* E, float* rhss) {
  __shared__ float Ec[T];
  int tid = threadIdx.x;
  int id = blockIdx.x * 256 + tid;       // (b*T+t)*N + m
  int m = id % N; int t = (id / N) % T; int b = id / (N * T);
  if (tid < T) Ec[tid] = E[(b * T + tid) * T + t];
  __syncthreads();
  const float* wr = w3x + ((size_t)b * N + m) * T;
  float acc = 0.f;
  #pragma unroll
  for (int tp = 0; tp < T; ++tp) acc += wr[tp] * Ec[tp];
  rhss[id] = acc;
}

__global__ void k_Slog(const float* lhss, const float* rhss, __hip_bfloat16* S) {
  __shared__ float rt[T][256];
  __shared__ float lt[16][T];
  int m0 = blockIdx.x * 256, n0 = blockIdx.y * 16, b = blockIdx.z;
  int tid = threadIdx.x;
  for (int t = 0; t < T; ++t) rt[t][tid] = rhss[((size_t)b * T + t) * N + m0 + tid];
  for (int i = tid; i < 16 * T; i += 256) {
    int n = i / T, t = i % T;
    lt[n][t] = lhss[((size_t)b * N + n0 + n) * T + t];
  }
  __syncthreads();
  #pragma unroll 4
  for (int n = 0; n < 16; ++n) {
    float acc = 0.f;
    #pragma unroll
    for (int t = 0; t < T; ++t) acc += lt[n][t] * rt[t][tid];
    S[((size_t)b * N + n0 + n) * N + m0 + tid] = __float2bfloat16(acc);
  }
}

__global__ void k_Ssm3(__hip_bfloat16* S) {
  int m = blockIdx.x * 256 + threadIdx.x; int b = blockIdx.y;
  size_t base = (size_t)b * N * N + m;
  float mx = -1e30f;
  for (int n = 0; n < N; ++n) mx = fmaxf(mx, b2f(S[base + (size_t)n * N]));
  float sum = 0.f;
  for (int n = 0; n < N; ++n) sum += expf(b2f(S[base + (size_t)n * N]) - mx);
  float inv = 1.f / sum;
  for (int n = 0; n < N; ++n) {
    size_t i = base + (size_t)n * N;
    S[i] = __float2bfloat16(expf(b2f(S[i]) - mx) * inv);
  }
}

// ---------------- GEMM operand prep (transpose to n-contiguous bf16) --------
// Abf[(k*Bc+bl)][m][n] = bf16(cheb[k,n,m] * S[b,n,m]); grid (N/64, N/64, 3*Bc)
__global__ __launch_bounds__(256) void k_prepA(const float* cheb,
                                               const __hip_bfloat16* S,
                                               unsigned short* Abf,
                                               int Bc, int b0) {
  __shared__ float Tl[64][65];
  int z = blockIdx.z;
  int k = z / Bc, bl = z % Bc, b = b0 + bl;
  int n0 = blockIdx.x * 64, m0 = blockIdx.y * 64;
  int tid = threadIdx.x;
  int j = tid & 63, i4 = tid >> 6;
  #pragma unroll
  for (int it = 0; it < 16; ++it) {
    int i = it * 4 + i4;
    Tl[i][j] = cheb[((size_t)k * N + n0 + i) * N + m0 + j] *
               b2f(S[((size_t)b * N + n0 + i) * N + m0 + j]);
  }
  __syncthreads();
  int i2 = (tid & 31) * 2, j8 = tid >> 5;
  #pragma unroll
  for (int it = 0; it < 8; ++it) {
    int jj = it * 8 + j8;
    unsigned u = (unsigned)f2bu(Tl[i2][jj]) | ((unsigned)f2bu(Tl[i2 + 1][jj]) << 16);
    *(unsigned*)&Abf[((size_t)z * N + m0 + jj) * N + n0 + i2] = u;
  }
}

// xT[bl][c'][n] = bf16(x[b,n,f,t]) with c' = t*32+f (kf-contiguous rk rows
// downstream). Read side identical/coalesced; only the write row is permuted.
// grid (N/64, FT/64=12, Bc)
__global__ __launch_bounds__(256) void k_prepX(const float* x, unsigned short* xT,
                                               int b0) {
  __shared__ float Tl[64][65];
  int bl = blockIdx.z, b = b0 + bl;
  int n0 = blockIdx.x * 64, c0 = blockIdx.y * 64;
  int tid = threadIdx.x;
  int j = tid & 63, i4 = tid >> 6;
  #pragma unroll
  for (int it = 0; it < 16; ++it) {
    int i = it * 4 + i4;
    Tl[i][j] = x[((size_t)b * N + n0 + i) * FT + c0 + j];
  }
  __syncthreads();
  int i2 = (tid & 31) * 2, j8 = tid >> 5;
  #pragma unroll
  for (int it = 0; it < 8; ++it) {
    int jj = it * 8 + j8;
    int c = c0 + jj;                       // old flat c = f*24+t
    int row = (c % 24) * 32 + c / 24;      // c' = t*32+f
    unsigned u = (unsigned)f2bu(Tl[i2][jj]) | ((unsigned)f2bu(Tl[i2 + 1][jj]) << 16);
    *(unsigned*)&xT[((size_t)bl * FT + row) * N + n0 + i2] = u;
  }
}

// weights -> bf16, MFMA-friendly layouts (ushort indices in wbf):
//   ThB  [o][kk=k*32+f] : [o*96 + kk]            0     .. 6143
//   tcwB [o][j*64+cc]   : [6144 + o*192 + ...]   6144  .. 18431
//   rcw pairs           : [18432 + (f>>1)*128 + o*2 + (f&1)]   .. 20479
__global__ void k_prepW(const float* Theta, const float* tcw, const float* rcw,
                        unsigned short* wbf) {
  int tid = threadIdx.x;
  for (int g = tid; g < 64 * 96; g += 256) {
    int o = g / 96, kk = g % 96;
    wbf[g] = f2bu(Theta[kk * 64 + o]);     // Theta[(k*32+f)*64 + o]
  }
  for (int g = tid; g < 64 * 192; g += 256) {
    int o = g / 192, r = g % 192;
    int jj = r / 64, cc = r % 64;
    wbf[6144 + g] = f2bu(tcw[o * 192 + cc * 3 + jj]);
  }
  for (int g = tid; g < 32 * 64; g += 256) {
    int f = g >> 6, o = g & 63;
    wbf[18432 + (f >> 1) * 128 + o * 2 + (f & 1)] = f2bu(rcw[o * 32 + f]);
  }
}

// ---------------- Chebyshev contraction: fused 3-k MFMA bf16 v2 -------------
// Both operands bf16, n-contiguous. Staging = pure 16B copies.
// Tile 64m x 128c x 64n; waves 2x2 (32m x 64c each). grid (6, 16, Bc).
__global__ __launch_bounds__(256) void k_gemm3(const unsigned short* Abf,
                                               const unsigned short* xT,
                                               float* rk, size_t kstride,
                                               int Bc) {
  __shared__ __align__(16) unsigned short A_l[3 * 64 * 72];   // 27648 B
  __shared__ __align__(16) unsigned short X_l[128 * 72];      // 18432 B
  int bl = blockIdx.z;
  int m0 = blockIdx.y * 64, c0 = blockIdx.x * 128;
  int tid = threadIdx.x;
  int lane = tid & 63, w = tid >> 6;
  int l15 = lane & 15, quad = lane >> 4;
  int wmi = w & 1, wci = w >> 1;
  int nh = lane & 7, ml = lane >> 3;

  f32x4 acc[3][2][4];
  #pragma unroll
  for (int k = 0; k < 3; ++k)
    #pragma unroll
    for (int mt = 0; mt < 2; ++mt)
      #pragma unroll
      for (int ct = 0; ct < 4; ++ct) acc[k][mt][ct] = (f32x4){0.f, 0.f, 0.f, 0.f};

  for (int n0 = 0; n0 < N; n0 += 64) {
    #pragma unroll
    for (int it = 0; it < 6; ++it) {               // A: 3k x 64m x 64n
      int k = it >> 1, mh = it & 1;
      int m = mh * 32 + w * 8 + ml;
      *(uint4*)&A_l[(k * 64 + m) * 72 + nh * 8] =
          *(const uint4*)&Abf[((size_t)(k * Bc + bl) * N + m0 + m) * N + n0 + nh * 8];
    }
    #pragma unroll
    for (int it = 0; it < 4; ++it) {               // X: 128c x 64n
      int c = it * 32 + w * 8 + ml;
      *(uint4*)&X_l[c * 72 + nh * 8] =
          *(const uint4*)&xT[((size_t)bl * FT + c0 + c) * N + n0 + nh * 8];
    }
    __syncthreads();
    #pragma unroll
    for (int ks = 0; ks < 2; ++ks) {
      int nf = ks * 32 + quad * 8;
      short8 bfr[4];
      #pragma unroll
      for (int ct = 0; ct < 4; ++ct)
        bfr[ct] = *(const short8*)&X_l[(wci * 64 + ct * 16 + l15) * 72 + nf];
      #pragma unroll
      for (int k = 0; k < 3; ++k)
        #pragma unroll
        for (int mt = 0; mt < 2; ++mt) {
          short8 af = *(const short8*)&A_l[(k * 64 + wmi * 32 + mt * 16 + l15) * 72 + nf];
          #pragma unroll
          for (int ct = 0; ct < 4; ++ct)
            acc[k][mt][ct] = __builtin_amdgcn_mfma_f32_16x16x32_bf16(
                af, bfr[ct], acc[k][mt][ct], 0, 0, 0);
        }
    }
    __syncthreads();
  }
  #pragma unroll
  for (int k = 0; k < 3; ++k)
    #pragma unroll
    for (int mt = 0; mt < 2; ++mt)
      #pragma unroll
      for (int ct = 0; ct < 4; ++ct) {
        int col = c0 + wci * 64 + ct * 16 + l15;
        #pragma unroll
        for (int r = 0; r < 4; ++r) {
          int row = m0 + wmi * 32 + mt * 16 + quad * 4 + r;
          rk[k * kstride + ((size_t)bl * N + row) * FT + col] = acc[k][mt][ct][r];
        }
      }
}

// ---------------- fused theta + conv (MFMA) + residual + LN -----------------
// block 256 = 4 waves; 4 m-rows; M = (m,t) = 96 rows. Wave w owns o-tile
// [w*16, w*16+16). grid = Bc*N/4.
// P0 stage rk->bf16 A_l[96][104] ; P1 theta MFMA (K=96) ; P2 sg bf16 LDS
// [m][t'][cc] XOR-swz, pad rows t'=0,25 ; P3 conv MFMA (K=192, im2col via
// t+j row offset) -> co_l[96][65] f32 ; P4 bias+residual+relu+LN per lane=o.
__global__ __launch_bounds__(256) void k_fuse(const float* rk, size_t kstride,
                                              const float* x,
                                              const unsigned short* wbf,
                                              const float* tcb, const float* rcb,
                                              const float* gam, const float* bet,
                                              float* out, int b0) {
  __shared__ __align__(16) unsigned char smem[38272];
  unsigned short* A_l = (unsigned short*)smem;      // [96][104] bf16 (phase 0-1)
  float* co_l = (float*)(smem + 13312);             // [96][65] f32 (phase 3-4)
  int tid = threadIdx.x;
  int w = tid >> 6, lane = tid & 63;
  int l15 = lane & 15, quad = lane >> 4;
  int r0l = blockIdx.x * 4;
  int o0 = w * 16;

  // B fragments from global (L1/L2-resident), register-held.
  short8 bth[3], btc[6];
  {
    int o = o0 + l15;
    #pragma unroll
    for (int ks = 0; ks < 3; ++ks)
      bth[ks] = *(const short8*)&wbf[o * 96 + ks * 32 + quad * 8];
    #pragma unroll
    for (int s = 0; s < 6; ++s)
      btc[s] = *(const short8*)&wbf[6144 + o * 192 + s * 32 + quad * 8];
  }

  // P0: A_l[(m*24+t)][k*32+f] = bf16(rk[k][r0l+m][t*32+f]); 2304 float4s.
  #pragma unroll
  for (int it = 0; it < 9; ++it) {
    int ch = it * 256 + tid;
    int k = ch / 768, r2 = ch % 768;
    int m = r2 / 192, r3 = r2 % 192;
    int t = r3 >> 3, fq = r3 & 7;
    const float4 v = *(const float4*)&rk[(size_t)k * kstride +
        (size_t)(r0l + m) * FT + t * 32 + fq * 4];
    unsigned long long pk = (unsigned long long)f2bu(v.x) |
        ((unsigned long long)f2bu(v.y) << 16) |
        ((unsigned long long)f2bu(v.z) << 32) |
        ((unsigned long long)f2bu(v.w) << 48);
    *(unsigned long long*)&A_l[(m * 24 + t) * 104 + k * 32 + fq * 4] = pk;
  }
  __syncthreads();

  // P1: theta MFMA, C[(m,t), o]; 6 M-tiles x K=3 steps.
  f32x4 th[6];
  #pragma unroll
  for (int Mt = 0; Mt < 6; ++Mt) {
    th[Mt] = (f32x4){0.f, 0.f, 0.f, 0.f};
    #pragma unroll
    for (int ks = 0; ks < 3; ++ks) {
      short8 af = *(const short8*)&A_l[(Mt * 16 + l15) * 104 + ks * 32 + quad * 8];
      th[Mt] = __builtin_amdgcn_mfma_f32_16x16x32_bf16(af, bth[ks], th[Mt], 0, 0, 0);
    }
  }
  __syncthreads();   // A_l dead; its space becomes sg_l

  // P2: sg_l[m][t'][cc] bf16, row byte-stride 128, XOR-swz key (row&7)<<4.
  // pad rows t'=0 and t'=25 zeroed (conv edge).
  #pragma unroll
  for (int e = tid; e < 512; e += 256) {
    int m = e >> 7, rr = (e >> 6) & 1, cc = e & 63;
    int rp = m * 26 + rr * 25;
    *(unsigned short*)(smem + rp * 128 + ((cc * 2) ^ ((rp & 7) << 4))) = 0;
  }
  #pragma unroll
  for (int Mt = 0; Mt < 6; ++Mt)
    #pragma unroll
    for (int r = 0; r < 4; ++r) {
      int row = Mt * 16 + quad * 4 + r;
      int m = row / 24, t = row % 24;
      int rp = m * 26 + t + 1;
      int cc = o0 + l15;
      *(unsigned short*)(smem + rp * 128 + ((cc * 2) ^ ((rp & 7) << 4))) =
          f2bu(fmaxf(th[Mt][r], 0.f));
    }
  __syncthreads();

  // P3: conv MFMA, K = 192 (j*64+cc); A row (m,t) col j*64+cc = sg[m][t+j][cc].
  f32x4 cv[6];
  #pragma unroll
  for (int Mt = 0; Mt < 6; ++Mt) {
    int row = Mt * 16 + l15;
    int m = row / 24, t = row % 24;
    cv[Mt] = (f32x4){0.f, 0.f, 0.f, 0.f};
    #pragma unroll
    for (int s = 0; s < 6; ++s) {
      int rp = m * 26 + t + (s >> 1);
      int cb = (32 * (s & 1) + quad * 8) * 2;
      short8 af = *(const short8*)(smem + rp * 128 + (cb ^ ((rp & 7) << 4)));
      cv[Mt] = __builtin_amdgcn_mfma_f32_16x16x32_bf16(af, btc[s], cv[Mt], 0, 0, 0);
    }
  }
  #pragma unroll
  for (int Mt = 0; Mt < 6; ++Mt)
    #pragma unroll
    for (int r = 0; r < 4; ++r) {
      int row = Mt * 16 + quad * 4 + r;
      co_l[row * 65 + o0 + l15] = cv[Mt][r];
    }
  __syncthreads();

  // P4: per-lane o; bias + residual (fp32) + relu + LN + store.
  int o = lane;
  float bias = tcb[o] + rcb[o];
  float acc[T];
  #pragma unroll
  for (int t = 0; t < T; ++t) acc[t] = co_l[(w * 24 + t) * 65 + o] + bias;

  size_t grow = (size_t)b0 * N + r0l + w;
  const float* xrow = x + grow * FT;
  const unsigned* rcp = (const unsigned*)(wbf + 18432);
  #pragma unroll 4
  for (int f2 = 0; f2 < 16; ++f2) {
    unsigned u = rcp[f2 * 64 + o];
    float wf0 = us2f((unsigned short)(u & 0xffffu));
    float wf1 = us2f((unsigned short)(u >> 16));
    const float4* xp0 = (const float4*)&xrow[(f2 * 2) * 24];     // wave-uniform
    const float4* xp1 = (const float4*)&xrow[(f2 * 2 + 1) * 24]; // broadcast
    #pragma unroll
    for (int q = 0; q < 6; ++q) {
      float4 v0 = xp0[q], v1 = xp1[q];
      acc[q * 4 + 0] += wf0 * v0.x + wf1 * v1.x;
      acc[q * 4 + 1] += wf0 * v0.y + wf1 * v1.y;
      acc[q * 4 + 2] += wf0 * v0.z + wf1 * v1.z;
      acc[q * 4 + 3] += wf0 * v0.w + wf1 * v1.w;
    }
  }
  float g = gam[o], be = bet[o];
  #pragma unroll
  for (int t = 0; t < T; ++t) {
    float z = fmaxf(acc[t], 0.f);
    float s = z, q = z * z;
    #pragma unroll
    for (int off = 1; off < 64; off <<= 1) {
      s += __shfl_xor(s, off);
      q += __shfl_xor(q, off);
    }
    float mu = s * (1.f / 64.f);
    float var = q * (1.f / 64.f) - mu * mu;
    acc[t] = (z - mu) * rsqrtf(var + 1e-5f) * g + be;
  }
  float* orow = out + grow * CTT + o * T;
  #pragma unroll
  for (int q = 0; q < 6; ++q)
    ((float4*)orow)[q] =
        make_float4(acc[q * 4], acc[q * 4 + 1], acc[q * 4 + 2], acc[q * 4 + 3]);
}

}  // namespace

extern "C" void kernel_launch(void* const* d_in, const int* in_sizes, int n_in,
                              void* d_out, int out_size, void* d_ws, size_t ws_size,
                              hipStream_t stream) {
  (void)in_sizes; (void)n_in; (void)out_size;
  const float* x     = (const float*)d_in[0];
  const float* W1    = (const float*)d_in[1];
  const float* W2    = (const float*)d_in[2];
  const float* W3    = (const float*)d_in[3];
  const float* U1    = (const float*)d_in[4];
  const float* U2    = (const float*)d_in[5];
  const float* U3    = (const float*)d_in[6];
  const float* cheb  = (const float*)d_in[7];
  const float* Theta = (const float*)d_in[8];
  const float* tcw   = (const float*)d_in[9];
  const float* tcb   = (const float*)d_in[10];
  const float* rcw   = (const float*)d_in[11];
  const float* rcb   = (const float*)d_in[12];
  const float* gam   = (const float*)d_in[13];
  const float* bet   = (const float*)d_in[14];
  float* out = (float*)d_out;

  // ---- runtime-adaptive workspace layout ----
  const size_t SB_BYTES = (size_t)B * N * N * 2;          // 33,554,432 (S bf16)
  const size_t WB_BYTES = 65536;                          // wbf (40960 used)
  const size_t AB_PER_B = (size_t)3 * N * N * 2;          // 6,291,456
  const size_t XT_PER_B = (size_t)FT * N * 2;             // 1,572,864
  const size_t RK_PER_B = (size_t)3 * N * FT * 4;         // 9,437,184
  const size_t SMALL = 2521472 * 4;                       // 10,085,888 B
  int Bc = 16;
  while (Bc > 1 && SB_BYTES + WB_BYTES + SMALL +
             (size_t)Bc * (AB_PER_B + XT_PER_B + RK_PER_B) > ws_size)
    Bc >>= 1;

  char* w = (char*)d_ws;
  __hip_bfloat16* Sb = (__hip_bfloat16*)w;
  unsigned short* wbf = (unsigned short*)(w + SB_BYTES);
  unsigned short* Abf = (unsigned short*)(w + SB_BYTES + WB_BYTES);
  unsigned short* xTb = (unsigned short*)(w + SB_BYTES + WB_BYTES +
                                          (size_t)Bc * AB_PER_B);
  float* rkbuf = (float*)(w + SB_BYTES + WB_BYTES +
                          (size_t)Bc * (AB_PER_B + XT_PER_B));
  size_t kstride = (size_t)Bc * N * FT;     // floats per k-bank of rk
  float* sm = (float*)(w + SB_BYTES + WB_BYTES +
                       (size_t)Bc * (AB_PER_B + XT_PER_B + RK_PER_B));
  float* lhst = sm;                       // B*T*F   = 12288
  float* lhs2 = lhst + B * T * F;         // B*T*N   = 393216
  float* rhst = lhs2 + B * T * N;         // B*N*T   = 393216
  float* w3x  = rhst + B * N * T;         // B*N*T   = 393216
  float* Elog = w3x + B * N * T;          // B*T*T   = 9216
  float* E    = Elog + B * T * T;         // B*T*T   = 9216
  float* EW1  = E + B * T * T;            // B*T     = 384
  float* tmp1 = EW1 + B * T;              // B*N*F   = 524288
  float* lhss = tmp1 + B * N * F;         // B*N*T   = 393216
  float* rhss = lhss + B * N * T;         // B*N*T   = 393216

  // temporal attention
  k_lhs_t<<<B * T * F, 64, 0, stream>>>(x, U1, lhst);
  k_lhs2<<<(B * T * N) / 256, 256, 0, stream>>>(lhst, U2, lhs2);
  k_fx<<<(B * N * T) / 256, 256, 0, stream>>>(x, U3, W3, rhst, w3x);
  k_Elog<<<B * T * T, 64, 0, stream>>>(lhs2, rhst, Elog);
  k_Esm<<<B, 64, 0, stream>>>(Elog, E);
  k_EW1<<<B, 64, 0, stream>>>(E, W1, EW1);

  // spatial attention (x_TAt folded out)
  k_tmp1x<<<(B * N * F) / 256, 256, 0, stream>>>(x, EW1, tmp1);
  k_lhs_s<<<(B * N * T) / 256, 256, 0, stream>>>(tmp1, W2, lhss);
  k_rhss<<<(B * N * T) / 256, 256, 0, stream>>>(w3x, E, rhss);
  k_Slog<<<dim3(N / 256, N / 16, B), 256, 0, stream>>>(lhss, rhss, Sb);
  k_Ssm3<<<dim3(N / 256, B), 256, 0, stream>>>(Sb);

  // weight prep (once)
  k_prepW<<<1, 256, 0, stream>>>(Theta, tcw, rcw, wbf);

  // per-chunk: operand prep + fused GEMM + fused epilogue
  for (int b0 = 0; b0 < B; b0 += Bc) {
    k_prepA<<<dim3(N / 64, N / 64, 3 * Bc), 256, 0, stream>>>(cheb, Sb, Abf, Bc, b0);
    k_prepX<<<dim3(N / 64, FT / 64, Bc), 256, 0, stream>>>(x, xTb, b0);
    k_gemm3<<<dim3(FT / 128, N / 64, Bc), 256, 0, stream>>>(Abf, xTb, rkbuf,
                                                            kstride, Bc);
    k_fuse<<<Bc * N / 4, 256, 0, stream>>>(rkbuf, kstride, x, wbf, tcb, rcb,
                                           gam, bet, out, b0);
  }
}

// Round 4
// 801.244 us; speedup vs baseline: 1.7039x; 1.3893x over previous
//
#include <hip/hip_runtime.h>
#include <hip/hip_bf16.h>
#include <math.h>

// ASTGCN block, MI355X. Round 10: kill k_Ssm3 (357us, 2.8% occupancy,
// 3 strided passes over S). Softmax over n is now: k_Ssum (segmented online
// max/sum reduction, 1024 blocks) + k_Scomb (combine 8 segment partials) +
// normalization folded into k_prepA's staging read (exp(S-mx)*inv applied
// where S was already being read). Removes 84MB of traffic and the
// latency-bound column walk. Everything else unchanged from round 9.

namespace {

constexpr int B = 16, N = 1024, F = 32, T = 24, CC = 64, CT = 64;
constexpr int FT = F * T;     // 768
constexpr int CTT = CT * T;   // 1536
constexpr int NSEG = 8;       // softmax n-segments

using f32x4  = __attribute__((ext_vector_type(4))) float;
using short8 = __attribute__((ext_vector_type(8))) short;

__device__ __forceinline__ float b2f(__hip_bfloat16 v) { return __bfloat162float(v); }
__device__ __forceinline__ unsigned short f2bu(float x) {   // fp32 -> bf16 bits, RNE
  union { float f; unsigned u; } c; c.f = x;
  unsigned u = c.u;
  return (unsigned short)((u + 0x7FFFu + ((u >> 16) & 1u)) >> 16);
}
__device__ __forceinline__ float us2f(unsigned short u) {   // bf16 bits -> fp32
  union { unsigned u; float f; } c; c.u = ((unsigned)u) << 16; return c.f;
}

// ---------------- temporal attention ----------------
__global__ void k_lhs_t(const float* x, const float* U1, float* lhst) {
  int bi = blockIdx.x;                 // (b*T+t)*F + f
  int f = bi % F; int t = (bi / F) % T; int b = bi / (F * T);
  int tid = threadIdx.x;
  float acc = 0.f;
  for (int n = tid; n < N; n += 64)
    acc += x[(((size_t)b * N + n) * F + f) * T + t] * U1[n];
  #pragma unroll
  for (int off = 32; off > 0; off >>= 1) acc += __shfl_down(acc, off);
  if (tid == 0) lhst[bi] = acc;
}

__global__ void k_lhs2(const float* lhst, const float* U2, float* lhs2) {
  __shared__ float ls[F];
  int tid = threadIdx.x;
  int id = blockIdx.x * 256 + tid;   // (b*T+t)*N + n
  int n = id % N; int bt = id / N;
  if (tid < F) ls[tid] = lhst[bt * F + tid];
  __syncthreads();
  float acc = 0.f;
  #pragma unroll
  for (int f = 0; f < F; ++f) acc += ls[f] * U2[f * N + n];
  lhs2[id] = acc;
}

__global__ void k_fx(const float* x, const float* U3, const float* W3,
                     float* rhst, float* w3x) {
  __shared__ float u3s[F], w3s[F];
  int tid = threadIdx.x;
  if (tid < F) { u3s[tid] = U3[tid]; w3s[tid] = W3[tid]; }
  __syncthreads();
  int id = blockIdx.x * 256 + tid;     // (b*N+n)*T + t
  int t = id % T; int bn = id / T;
  float au = 0.f, aw = 0.f;
  #pragma unroll
  for (int f = 0; f < F; ++f) {
    float v = x[((size_t)bn * F + f) * T + t];
    au += u3s[f] * v; aw += w3s[f] * v;
  }
  rhst[id] = au; w3x[id] = aw;
}

__global__ void k_Elog(const float* lhs2, const float* rhst, float* Elog) {
  int bi = blockIdx.x;                 // (b*T+t)*T + s
  int s = bi % T; int t = (bi / T) % T; int b = bi / (T * T);
  int tid = threadIdx.x;
  float acc = 0.f;
  for (int n = tid; n < N; n += 64)
    acc += lhs2[(b * T + t) * N + n] * rhst[(b * N + n) * T + s];
  #pragma unroll
  for (int off = 32; off > 0; off >>= 1) acc += __shfl_down(acc, off);
  if (tid == 0) Elog[bi] = acc;
}

__global__ void k_Esm(const float* Elog, float* E) {
  int b = blockIdx.x; int s = threadIdx.x;
  if (s >= T) return;
  float mx = -1e30f;
  for (int t = 0; t < T; ++t) mx = fmaxf(mx, Elog[(b * T + t) * T + s]);
  float sum = 0.f;
  for (int t = 0; t < T; ++t) sum += expf(Elog[(b * T + t) * T + s] - mx);
  float inv = 1.f / sum;
  for (int t = 0; t < T; ++t)
    E[(b * T + t) * T + s] = expf(Elog[(b * T + t) * T + s] - mx) * inv;
}

__global__ void k_EW1(const float* E, const float* W1, float* EW1) {
  int b = blockIdx.x; int t = threadIdx.x;
  if (t >= T) return;
  float acc = 0.f;
  for (int s = 0; s < T; ++s) acc += E[(b * T + t) * T + s] * W1[s];
  EW1[b * T + t] = acc;
}

// ---------------- spatial attention ----------------
__global__ void k_tmp1x(const float* x, const float* EW1, float* tmp1) {
  __shared__ float ew[T];
  int tid = threadIdx.x;
  int id = blockIdx.x * 256 + tid;       // (b*N+n)*F + f
  int b = id / (N * F);
  if (tid < T) ew[tid] = EW1[b * T + tid];
  __syncthreads();
  const float* xr = x + (size_t)id * T;
  float acc = 0.f;
  #pragma unroll
  for (int t = 0; t < T; ++t) acc += xr[t] * ew[t];
  tmp1[id] = acc;
}

__global__ void k_lhs_s(const float* tmp1, const float* W2, float* lhss) {
  int id = blockIdx.x * 256 + threadIdx.x;
  int t = id % T; int bn = id / T;
  float acc = 0.f;
  #pragma unroll
  for (int f = 0; f < F; ++f) acc += tmp1[bn * F + f] * W2[f * T + t];
  lhss[id] = acc;
}

__global__ void k_rhss(const float* w3x, const float* E, float* rhss) {
  __shared__ float Ec[T];
  int tid = threadIdx.x;
  int id = blockIdx.x * 256 + tid;       // (b*T+t)*N + m
  int m = id % N; int t = (id / N) % T; int b = id / (N * T);
  if (tid < T) Ec[tid] = E[(b * T + tid) * T + t];
  __syncthreads();
  const float* wr = w3x + ((size_t)b * N + m) * T;
  float acc = 0.f;
  #pragma unroll
  for (int tp = 0; tp < T; ++tp) acc += wr[tp] * Ec[tp];
  rhss[id] = acc;
}

__global__ void k_Slog(const float* lhss, const float* rhss, __hip_bfloat16* S) {
  __shared__ float rt[T][256];
  __shared__ float lt[16][T];
  int m0 = blockIdx.x * 256, n0 = blockIdx.y * 16, b = blockIdx.z;
  int tid = threadIdx.x;
  for (int t = 0; t < T; ++t) rt[t][tid] = rhss[((size_t)b * T + t) * N + m0 + tid];
  for (int i = tid; i < 16 * T; i += 256) {
    int n = i / T, t = i % T;
    lt[n][t] = lhss[((size_t)b * N + n0 + n) * T + t];
  }
  __syncthreads();
  #pragma unroll 4
  for (int n = 0; n < 16; ++n) {
    float acc = 0.f;
    #pragma unroll
    for (int t = 0; t < T; ++t) acc += lt[n][t] * rt[t][tid];
    S[((size_t)b * N + n0 + n) * N + m0 + tid] = __float2bfloat16(acc);
  }
}

// ---------------- column softmax stats (replaces k_Ssm3) --------------------
// Online (max, rescaled-sum) over n-segment of 128 rows; 128 columns/block.
// partials layout [seg][b][m] so writes are coalesced. grid (N/128, B, NSEG).
__global__ __launch_bounds__(256) void k_Ssum(const __hip_bfloat16* S,
                                              float* pmx, float* psm) {
  int m0 = blockIdx.x * 128; int b = blockIdx.y; int z = blockIdx.z;
  int tid = threadIdx.x;
  int lane = tid & 63, nq = tid >> 6;
  int c = m0 + lane * 2;
  float mx0 = -1e30f, sm0 = 0.f, mx1 = -1e30f, sm1 = 0.f;
  #pragma unroll 4
  for (int i = 0; i < 32; ++i) {
    int n = z * 128 + i * 4 + nq;
    unsigned u = *(const unsigned*)&S[((size_t)b * N + n) * N + c];
    float v0 = us2f((unsigned short)(u & 0xffffu));
    float v1 = us2f((unsigned short)(u >> 16));
    float nm0 = fmaxf(mx0, v0);
    sm0 = sm0 * __expf(mx0 - nm0) + __expf(v0 - nm0); mx0 = nm0;
    float nm1 = fmaxf(mx1, v1);
    sm1 = sm1 * __expf(mx1 - nm1) + __expf(v1 - nm1); mx1 = nm1;
  }
  __shared__ float lmx[4][128], lsm[4][128];
  lmx[nq][lane * 2] = mx0; lmx[nq][lane * 2 + 1] = mx1;
  lsm[nq][lane * 2] = sm0; lsm[nq][lane * 2 + 1] = sm1;
  __syncthreads();
  if (nq == 0) {
    #pragma unroll
    for (int cc2 = 0; cc2 < 2; ++cc2) {
      int col = lane * 2 + cc2;
      float M = lmx[0][col], Sg = lsm[0][col];
      #pragma unroll
      for (int s = 1; s < 4; ++s) {
        float m2 = lmx[s][col], s2 = lsm[s][col];
        float nm = fmaxf(M, m2);
        Sg = Sg * __expf(M - nm) + s2 * __expf(m2 - nm);
        M = nm;
      }
      pmx[((size_t)z * B + b) * N + m0 + col] = M;
      psm[((size_t)z * B + b) * N + m0 + col] = Sg;
    }
  }
}

// combine NSEG partials -> smax, sinv per (b,m). grid (B*N/256).
__global__ void k_Scomb(const float* pmx, const float* psm,
                        float* smax, float* sinv) {
  int id = blockIdx.x * 256 + threadIdx.x;   // b*N + m
  float M = -1e30f, Sg = 0.f;
  #pragma unroll
  for (int z = 0; z < NSEG; ++z) {
    float m2 = pmx[(size_t)z * B * N + id];
    float s2 = psm[(size_t)z * B * N + id];
    float nm = fmaxf(M, m2);
    Sg = Sg * __expf(M - nm) + s2 * __expf(m2 - nm);
    M = nm;
  }
  smax[id] = M;
  sinv[id] = 1.f / Sg;
}

// ---------------- GEMM operand prep (transpose to n-contiguous bf16) --------
// Abf[(k*Bc+bl)][m][n] = bf16(cheb[k,n,m] * softmax(S)[b,n,m]); softmax
// normalization applied inline from smax/sinv. grid (N/64, N/64, 3*Bc)
__global__ __launch_bounds__(256) void k_prepA(const float* cheb,
                                               const __hip_bfloat16* S,
                                               const float* smax,
                                               const float* sinv,
                                               unsigned short* Abf,
                                               int Bc, int b0) {
  __shared__ float Tl[64][65];
  int z = blockIdx.z;
  int k = z / Bc, bl = z % Bc, b = b0 + bl;
  int n0 = blockIdx.x * 64, m0 = blockIdx.y * 64;
  int tid = threadIdx.x;
  int j = tid & 63, i4 = tid >> 6;
  float cm = smax[(size_t)b * N + m0 + j];
  float ci = sinv[(size_t)b * N + m0 + j];
  #pragma unroll
  for (int it = 0; it < 16; ++it) {
    int i = it * 4 + i4;
    Tl[i][j] = cheb[((size_t)k * N + n0 + i) * N + m0 + j] *
               (__expf(b2f(S[((size_t)b * N + n0 + i) * N + m0 + j]) - cm) * ci);
  }
  __syncthreads();
  int i2 = (tid & 31) * 2, j8 = tid >> 5;
  #pragma unroll
  for (int it = 0; it < 8; ++it) {
    int jj = it * 8 + j8;
    unsigned u = (unsigned)f2bu(Tl[i2][jj]) | ((unsigned)f2bu(Tl[i2 + 1][jj]) << 16);
    *(unsigned*)&Abf[((size_t)z * N + m0 + jj) * N + n0 + i2] = u;
  }
}

// xT[bl][c'][n] = bf16(x[b,n,f,t]) with c' = t*32+f (kf-contiguous rk rows
// downstream). Read side identical/coalesced; only the write row is permuted.
// grid (N/64, FT/64=12, Bc)
__global__ __launch_bounds__(256) void k_prepX(const float* x, unsigned short* xT,
                                               int b0) {
  __shared__ float Tl[64][65];
  int bl = blockIdx.z, b = b0 + bl;
  int n0 = blockIdx.x * 64, c0 = blockIdx.y * 64;
  int tid = threadIdx.x;
  int j = tid & 63, i4 = tid >> 6;
  #pragma unroll
  for (int it = 0; it < 16; ++it) {
    int i = it * 4 + i4;
    Tl[i][j] = x[((size_t)b * N + n0 + i) * FT + c0 + j];
  }
  __syncthreads();
  int i2 = (tid & 31) * 2, j8 = tid >> 5;
  #pragma unroll
  for (int it = 0; it < 8; ++it) {
    int jj = it * 8 + j8;
    int c = c0 + jj;                       // old flat c = f*24+t
    int row = (c % 24) * 32 + c / 24;      // c' = t*32+f
    unsigned u = (unsigned)f2bu(Tl[i2][jj]) | ((unsigned)f2bu(Tl[i2 + 1][jj]) << 16);
    *(unsigned*)&xT[((size_t)bl * FT + row) * N + n0 + i2] = u;
  }
}

// weights -> bf16, MFMA-friendly layouts (ushort indices in wbf):
//   ThB  [o][kk=k*32+f] : [o*96 + kk]            0     .. 6143
//   tcwB [o][j*64+cc]   : [6144 + o*192 + ...]   6144  .. 18431
//   rcw pairs           : [18432 + (f>>1)*128 + o*2 + (f&1)]   .. 20479
__global__ void k_prepW(const float* Theta, const float* tcw, const float* rcw,
                        unsigned short* wbf) {
  int tid = threadIdx.x;
  for (int g = tid; g < 64 * 96; g += 256) {
    int o = g / 96, kk = g % 96;
    wbf[g] = f2bu(Theta[kk * 64 + o]);     // Theta[(k*32+f)*64 + o]
  }
  for (int g = tid; g < 64 * 192; g += 256) {
    int o = g / 192, r = g % 192;
    int jj = r / 64, cc = r % 64;
    wbf[6144 + g] = f2bu(tcw[o * 192 + cc * 3 + jj]);
  }
  for (int g = tid; g < 32 * 64; g += 256) {
    int f = g >> 6, o = g & 63;
    wbf[18432 + (f >> 1) * 128 + o * 2 + (f & 1)] = f2bu(rcw[o * 32 + f]);
  }
}

// ---------------- Chebyshev contraction: fused 3-k MFMA bf16 v2 -------------
// Both operands bf16, n-contiguous. Staging = pure 16B copies.
// Tile 64m x 128c x 64n; waves 2x2 (32m x 64c each). grid (6, 16, Bc).
__global__ __launch_bounds__(256) void k_gemm3(const unsigned short* Abf,
                                               const unsigned short* xT,
                                               float* rk, size_t kstride,
                                               int Bc) {
  __shared__ __align__(16) unsigned short A_l[3 * 64 * 72];   // 27648 B
  __shared__ __align__(16) unsigned short X_l[128 * 72];      // 18432 B
  int bl = blockIdx.z;
  int m0 = blockIdx.y * 64, c0 = blockIdx.x * 128;
  int tid = threadIdx.x;
  int lane = tid & 63, w = tid >> 6;
  int l15 = lane & 15, quad = lane >> 4;
  int wmi = w & 1, wci = w >> 1;
  int nh = lane & 7, ml = lane >> 3;

  f32x4 acc[3][2][4];
  #pragma unroll
  for (int k = 0; k < 3; ++k)
    #pragma unroll
    for (int mt = 0; mt < 2; ++mt)
      #pragma unroll
      for (int ct = 0; ct < 4; ++ct) acc[k][mt][ct] = (f32x4){0.f, 0.f, 0.f, 0.f};

  for (int n0 = 0; n0 < N; n0 += 64) {
    #pragma unroll
    for (int it = 0; it < 6; ++it) {               // A: 3k x 64m x 64n
      int k = it >> 1, mh = it & 1;
      int m = mh * 32 + w * 8 + ml;
      *(uint4*)&A_l[(k * 64 + m) * 72 + nh * 8] =
          *(const uint4*)&Abf[((size_t)(k * Bc + bl) * N + m0 + m) * N + n0 + nh * 8];
    }
    #pragma unroll
    for (int it = 0; it < 4; ++it) {               // X: 128c x 64n
      int c = it * 32 + w * 8 + ml;
      *(uint4*)&X_l[c * 72 + nh * 8] =
          *(const uint4*)&xT[((size_t)bl * FT + c0 + c) * N + n0 + nh * 8];
    }
    __syncthreads();
    #pragma unroll
    for (int ks = 0; ks < 2; ++ks) {
      int nf = ks * 32 + quad * 8;
      short8 bfr[4];
      #pragma unroll
      for (int ct = 0; ct < 4; ++ct)
        bfr[ct] = *(const short8*)&X_l[(wci * 64 + ct * 16 + l15) * 72 + nf];
      #pragma unroll
      for (int k = 0; k < 3; ++k)
        #pragma unroll
        for (int mt = 0; mt < 2; ++mt) {
          short8 af = *(const short8*)&A_l[(k * 64 + wmi * 32 + mt * 16 + l15) * 72 + nf];
          #pragma unroll
          for (int ct = 0; ct < 4; ++ct)
            acc[k][mt][ct] = __builtin_amdgcn_mfma_f32_16x16x32_bf16(
                af, bfr[ct], acc[k][mt][ct], 0, 0, 0);
        }
    }
    __syncthreads();
  }
  #pragma unroll
  for (int k = 0; k < 3; ++k)
    #pragma unroll
    for (int mt = 0; mt < 2; ++mt)
      #pragma unroll
      for (int ct = 0; ct < 4; ++ct) {
        int col = c0 + wci * 64 + ct * 16 + l15;
        #pragma unroll
        for (int r = 0; r < 4; ++r) {
          int row = m0 + wmi * 32 + mt * 16 + quad * 4 + r;
          rk[k * kstride + ((size_t)bl * N + row) * FT + col] = acc[k][mt][ct][r];
        }
      }
}

// ---------------- fused theta + conv (MFMA) + residual + LN -----------------
// block 256 = 4 waves; 4 m-rows; M = (m,t) = 96 rows. Wave w owns o-tile
// [w*16, w*16+16). grid = Bc*N/4.
__global__ __launch_bounds__(256) void k_fuse(const float* rk, size_t kstride,
                                              const float* x,
                                              const unsigned short* wbf,
                                              const float* tcb, const float* rcb,
                                              const float* gam, const float* bet,
                                              float* out, int b0) {
  __shared__ __align__(16) unsigned char smem[38272];
  unsigned short* A_l = (unsigned short*)smem;      // [96][104] bf16 (phase 0-1)
  float* co_l = (float*)(smem + 13312);             // [96][65] f32 (phase 3-4)
  int tid = threadIdx.x;
  int w = tid >> 6, lane = tid & 63;
  int l15 = lane & 15, quad = lane >> 4;
  int r0l = blockIdx.x * 4;
  int o0 = w * 16;

  // B fragments from global (L1/L2-resident), register-held.
  short8 bth[3], btc[6];
  {
    int o = o0 + l15;
    #pragma unroll
    for (int ks = 0; ks < 3; ++ks)
      bth[ks] = *(const short8*)&wbf[o * 96 + ks * 32 + quad * 8];
    #pragma unroll
    for (int s = 0; s < 6; ++s)
      btc[s] = *(const short8*)&wbf[6144 + o * 192 + s * 32 + quad * 8];
  }

  // P0: A_l[(m*24+t)][k*32+f] = bf16(rk[k][r0l+m][t*32+f]); 2304 float4s.
  #pragma unroll
  for (int it = 0; it < 9; ++it) {
    int ch = it * 256 + tid;
    int k = ch / 768, r2 = ch % 768;
    int m = r2 / 192, r3 = r2 % 192;
    int t = r3 >> 3, fq = r3 & 7;
    const float4 v = *(const float4*)&rk[(size_t)k * kstride +
        (size_t)(r0l + m) * FT + t * 32 + fq * 4];
    unsigned long long pk = (unsigned long long)f2bu(v.x) |
        ((unsigned long long)f2bu(v.y) << 16) |
        ((unsigned long long)f2bu(v.z) << 32) |
        ((unsigned long long)f2bu(v.w) << 48);
    *(unsigned long long*)&A_l[(m * 24 + t) * 104 + k * 32 + fq * 4] = pk;
  }
  __syncthreads();

  // P1: theta MFMA, C[(m,t), o]; 6 M-tiles x K=3 steps.
  f32x4 th[6];
  #pragma unroll
  for (int Mt = 0; Mt < 6; ++Mt) {
    th[Mt] = (f32x4){0.f, 0.f, 0.f, 0.f};
    #pragma unroll
    for (int ks = 0; ks < 3; ++ks) {
      short8 af = *(const short8*)&A_l[(Mt * 16 + l15) * 104 + ks * 32 + quad * 8];
      th[Mt] = __builtin_amdgcn_mfma_f32_16x16x32_bf16(af, bth[ks], th[Mt], 0, 0, 0);
    }
  }
  __syncthreads();   // A_l dead; its space becomes sg_l

  // P2: sg_l[m][t'][cc] bf16, row byte-stride 128, XOR-swz key (row&7)<<4.
  // pad rows t'=0 and t'=25 zeroed (conv edge).
  #pragma unroll
  for (int e = tid; e < 512; e += 256) {
    int m = e >> 7, rr = (e >> 6) & 1, cc = e & 63;
    int rp = m * 26 + rr * 25;
    *(unsigned short*)(smem + rp * 128 + ((cc * 2) ^ ((rp & 7) << 4))) = 0;
  }
  #pragma unroll
  for (int Mt = 0; Mt < 6; ++Mt)
    #pragma unroll
    for (int r = 0; r < 4; ++r) {
      int row = Mt * 16 + quad * 4 + r;
      int m = row / 24, t = row % 24;
      int rp = m * 26 + t + 1;
      int cc = o0 + l15;
      *(unsigned short*)(smem + rp * 128 + ((cc * 2) ^ ((rp & 7) << 4))) =
          f2bu(fmaxf(th[Mt][r], 0.f));
    }
  __syncthreads();

  // P3: conv MFMA, K = 192 (j*64+cc); A row (m,t) col j*64+cc = sg[m][t+j][cc].
  f32x4 cv[6];
  #pragma unroll
  for (int Mt = 0; Mt < 6; ++Mt) {
    int row = Mt * 16 + l15;
    int m = row / 24, t = row % 24;
    cv[Mt] = (f32x4){0.f, 0.f, 0.f, 0.f};
    #pragma unroll
    for (int s = 0; s < 6; ++s) {
      int rp = m * 26 + t + (s >> 1);
      int cb = (32 * (s & 1) + quad * 8) * 2;
      short8 af = *(const short8*)(smem + rp * 128 + (cb ^ ((rp & 7) << 4)));
      cv[Mt] = __builtin_amdgcn_mfma_f32_16x16x32_bf16(af, btc[s], cv[Mt], 0, 0, 0);
    }
  }
  #pragma unroll
  for (int Mt = 0; Mt < 6; ++Mt)
    #pragma unroll
    for (int r = 0; r < 4; ++r) {
      int row = Mt * 16 + quad * 4 + r;
      co_l[row * 65 + o0 + l15] = cv[Mt][r];
    }
  __syncthreads();

  // P4: per-lane o; bias + residual (fp32) + relu + LN + store.
  int o = lane;
  float bias = tcb[o] + rcb[o];
  float acc[T];
  #pragma unroll
  for (int t = 0; t < T; ++t) acc[t] = co_l[(w * 24 + t) * 65 + o] + bias;

  size_t grow = (size_t)b0 * N + r0l + w;
  const float* xrow = x + grow * FT;
  const unsigned* rcp = (const unsigned*)(wbf + 18432);
  #pragma unroll 4
  for (int f2 = 0; f2 < 16; ++f2) {
    unsigned u = rcp[f2 * 64 + o];
    float wf0 = us2f((unsigned short)(u & 0xffffu));
    float wf1 = us2f((unsigned short)(u >> 16));
    const float4* xp0 = (const float4*)&xrow[(f2 * 2) * 24];     // wave-uniform
    const float4* xp1 = (const float4*)&xrow[(f2 * 2 + 1) * 24]; // broadcast
    #pragma unroll
    for (int q = 0; q < 6; ++q) {
      float4 v0 = xp0[q], v1 = xp1[q];
      acc[q * 4 + 0] += wf0 * v0.x + wf1 * v1.x;
      acc[q * 4 + 1] += wf0 * v0.y + wf1 * v1.y;
      acc[q * 4 + 2] += wf0 * v0.z + wf1 * v1.z;
      acc[q * 4 + 3] += wf0 * v0.w + wf1 * v1.w;
    }
  }
  float g = gam[o], be = bet[o];
  #pragma unroll
  for (int t = 0; t < T; ++t) {
    float z = fmaxf(acc[t], 0.f);
    float s = z, q = z * z;
    #pragma unroll
    for (int off = 1; off < 64; off <<= 1) {
      s += __shfl_xor(s, off);
      q += __shfl_xor(q, off);
    }
    float mu = s * (1.f / 64.f);
    float var = q * (1.f / 64.f) - mu * mu;
    acc[t] = (z - mu) * rsqrtf(var + 1e-5f) * g + be;
  }
  float* orow = out + grow * CTT + o * T;
  #pragma unroll
  for (int q = 0; q < 6; ++q)
    ((float4*)orow)[q] =
        make_float4(acc[q * 4], acc[q * 4 + 1], acc[q * 4 + 2], acc[q * 4 + 3]);
}

}  // namespace

extern "C" void kernel_launch(void* const* d_in, const int* in_sizes, int n_in,
                              void* d_out, int out_size, void* d_ws, size_t ws_size,
                              hipStream_t stream) {
  (void)in_sizes; (void)n_in; (void)out_size;
  const float* x     = (const float*)d_in[0];
  const float* W1    = (const float*)d_in[1];
  const float* W2    = (const float*)d_in[2];
  const float* W3    = (const float*)d_in[3];
  const float* U1    = (const float*)d_in[4];
  const float* U2    = (const float*)d_in[5];
  const float* U3    = (const float*)d_in[6];
  const float* cheb  = (const float*)d_in[7];
  const float* Theta = (const float*)d_in[8];
  const float* tcw   = (const float*)d_in[9];
  const float* tcb   = (const float*)d_in[10];
  const float* rcw   = (const float*)d_in[11];
  const float* rcb   = (const float*)d_in[12];
  const float* gam   = (const float*)d_in[13];
  const float* bet   = (const float*)d_in[14];
  float* out = (float*)d_out;

  // ---- runtime-adaptive workspace layout ----
  const size_t SB_BYTES = (size_t)B * N * N * 2;          // 33,554,432 (S bf16)
  const size_t WB_BYTES = 65536;                          // wbf (40960 used)
  const size_t AB_PER_B = (size_t)3 * N * N * 2;          // 6,291,456
  const size_t XT_PER_B = (size_t)FT * N * 2;             // 1,572,864
  const size_t RK_PER_B = (size_t)3 * N * FT * 4;         // 9,437,184
  const size_t SMALL = 2816384 * 4;                       // 11,265,536 B
  int Bc = 16;
  while (Bc > 1 && SB_BYTES + WB_BYTES + SMALL +
             (size_t)Bc * (AB_PER_B + XT_PER_B + RK_PER_B) > ws_size)
    Bc >>= 1;

  char* w = (char*)d_ws;
  __hip_bfloat16* Sb = (__hip_bfloat16*)w;
  unsigned short* wbf = (unsigned short*)(w + SB_BYTES);
  unsigned short* Abf = (unsigned short*)(w + SB_BYTES + WB_BYTES);
  unsigned short* xTb = (unsigned short*)(w + SB_BYTES + WB_BYTES +
                                          (size_t)Bc * AB_PER_B);
  float* rkbuf = (float*)(w + SB_BYTES + WB_BYTES +
                          (size_t)Bc * (AB_PER_B + XT_PER_B));
  size_t kstride = (size_t)Bc * N * FT;     // floats per k-bank of rk
  float* sm = (float*)(w + SB_BYTES + WB_BYTES +
                       (size_t)Bc * (AB_PER_B + XT_PER_B + RK_PER_B));
  float* lhst = sm;                       // B*T*F   = 12288
  float* lhs2 = lhst + B * T * F;         // B*T*N   = 393216
  float* rhst = lhs2 + B * T * N;         // B*N*T   = 393216
  float* w3x  = rhst + B * N * T;         // B*N*T   = 393216
  float* Elog = w3x + B * N * T;          // B*T*T   = 9216
  float* E    = Elog + B * T * T;         // B*T*T   = 9216
  float* EW1  = E + B * T * T;            // B*T     = 384
  float* tmp1 = EW1 + B * T;              // B*N*F   = 524288
  float* lhss = tmp1 + B * N * F;         // B*N*T   = 393216
  float* rhss = lhss + B * N * T;         // B*N*T   = 393216
  float* pmx  = rhss + B * N * T;         // NSEG*B*N = 131072
  float* psm  = pmx + NSEG * B * N;       // NSEG*B*N = 131072
  float* smax = psm + NSEG * B * N;       // B*N     = 16384
  float* sinv = smax + B * N;             // B*N     = 16384

  // temporal attention
  k_lhs_t<<<B * T * F, 64, 0, stream>>>(x, U1, lhst);
  k_lhs2<<<(B * T * N) / 256, 256, 0, stream>>>(lhst, U2, lhs2);
  k_fx<<<(B * N * T) / 256, 256, 0, stream>>>(x, U3, W3, rhst, w3x);
  k_Elog<<<B * T * T, 64, 0, stream>>>(lhs2, rhst, Elog);
  k_Esm<<<B, 64, 0, stream>>>(Elog, E);
  k_EW1<<<B, 64, 0, stream>>>(E, W1, EW1);

  // spatial attention (x_TAt folded out)
  k_tmp1x<<<(B * N * F) / 256, 256, 0, stream>>>(x, EW1, tmp1);
  k_lhs_s<<<(B * N * T) / 256, 256, 0, stream>>>(tmp1, W2, lhss);
  k_rhss<<<(B * N * T) / 256, 256, 0, stream>>>(w3x, E, rhss);
  k_Slog<<<dim3(N / 256, N / 16, B), 256, 0, stream>>>(lhss, rhss, Sb);
  k_Ssum<<<dim3(N / 128, B, NSEG), 256, 0, stream>>>(Sb, pmx, psm);
  k_Scomb<<<(B * N) / 256, 256, 0, stream>>>(pmx, psm, smax, sinv);

  // weight prep (once)
  k_prepW<<<1, 256, 0, stream>>>(Theta, tcw, rcw, wbf);

  // per-chunk: operand prep + fused GEMM + fused epilogue
  for (int b0 = 0; b0 < B; b0 += Bc) {
    k_prepA<<<dim3(N / 64, N / 64, 3 * Bc), 256, 0, stream>>>(cheb, Sb, smax,
                                                              sinv, Abf, Bc, b0);
    k_prepX<<<dim3(N / 64, FT / 64, Bc), 256, 0, stream>>>(x, xTb, b0);
    k_gemm3<<<dim3(FT / 128, N / 64, Bc), 256, 0, stream>>>(Abf, xTb, rkbuf,
                                                            kstride, Bc);
    k_fuse<<<Bc * N / 4, 256, 0, stream>>>(rkbuf, kstride, x, wbf, tcb, rcb,
                                           gam, bet, out, b0);
  }
}

// Round 5
// 682.902 us; speedup vs baseline: 1.9991x; 1.1733x over previous
//
#include <hip/hip_runtime.h>
#include <hip/hip_bf16.h>
#include <math.h>

// ASTGCN block, MI355X. Round 11: k_gemm3 staging moved to
// __builtin_amdgcn_global_load_lds width=16 (was reg-staged: the naked
// per-K-step load latency held MfmaUtil at 12.6%). LDS stride 72->64 (linear
// dest required by gload_lds), conflicts fixed rule-21 style: per-lane
// XOR-pre-swizzled GLOBAL source chunk (nh^ml) + matching XOR on LDS read
// ((row&7)) -> every 16B slot serves exactly 2 lanes (free). LDS 46080->40960
// => 4 blocks/CU (4*40960 = 160KiB exactly). Prep kernels unchanged.

namespace {

constexpr int B = 16, N = 1024, F = 32, T = 24, CC = 64, CT = 64;
constexpr int FT = F * T;     // 768
constexpr int CTT = CT * T;   // 1536
constexpr int NSEG = 8;       // softmax n-segments

using f32x4  = __attribute__((ext_vector_type(4))) float;
using short8 = __attribute__((ext_vector_type(8))) short;

__device__ __forceinline__ float b2f(__hip_bfloat16 v) { return __bfloat162float(v); }
__device__ __forceinline__ unsigned short f2bu(float x) {   // fp32 -> bf16 bits, RNE
  union { float f; unsigned u; } c; c.f = x;
  unsigned u = c.u;
  return (unsigned short)((u + 0x7FFFu + ((u >> 16) & 1u)) >> 16);
}
__device__ __forceinline__ float us2f(unsigned short u) {   // bf16 bits -> fp32
  union { unsigned u; float f; } c; c.u = ((unsigned)u) << 16; return c.f;
}
__device__ __forceinline__ void gload16(const void* g, void* l) {
  __builtin_amdgcn_global_load_lds(
      (const __attribute__((address_space(1))) unsigned int*)g,
      (__attribute__((address_space(3))) unsigned int*)l, 16, 0, 0);
}

// ---------------- temporal attention ----------------
__global__ void k_lhs_t(const float* x, const float* U1, float* lhst) {
  int bi = blockIdx.x;                 // (b*T+t)*F + f
  int f = bi % F; int t = (bi / F) % T; int b = bi / (F * T);
  int tid = threadIdx.x;
  float acc = 0.f;
  for (int n = tid; n < N; n += 64)
    acc += x[(((size_t)b * N + n) * F + f) * T + t] * U1[n];
  #pragma unroll
  for (int off = 32; off > 0; off >>= 1) acc += __shfl_down(acc, off);
  if (tid == 0) lhst[bi] = acc;
}

__global__ void k_lhs2(const float* lhst, const float* U2, float* lhs2) {
  __shared__ float ls[F];
  int tid = threadIdx.x;
  int id = blockIdx.x * 256 + tid;   // (b*T+t)*N + n
  int n = id % N; int bt = id / N;
  if (tid < F) ls[tid] = lhst[bt * F + tid];
  __syncthreads();
  float acc = 0.f;
  #pragma unroll
  for (int f = 0; f < F; ++f) acc += ls[f] * U2[f * N + n];
  lhs2[id] = acc;
}

__global__ void k_fx(const float* x, const float* U3, const float* W3,
                     float* rhst, float* w3x) {
  __shared__ float u3s[F], w3s[F];
  int tid = threadIdx.x;
  if (tid < F) { u3s[tid] = U3[tid]; w3s[tid] = W3[tid]; }
  __syncthreads();
  int id = blockIdx.x * 256 + tid;     // (b*N+n)*T + t
  int t = id % T; int bn = id / T;
  float au = 0.f, aw = 0.f;
  #pragma unroll
  for (int f = 0; f < F; ++f) {
    float v = x[((size_t)bn * F + f) * T + t];
    au += u3s[f] * v; aw += w3s[f] * v;
  }
  rhst[id] = au; w3x[id] = aw;
}

__global__ void k_Elog(const float* lhs2, const float* rhst, float* Elog) {
  int bi = blockIdx.x;                 // (b*T+t)*T + s
  int s = bi % T; int t = (bi / T) % T; int b = bi / (T * T);
  int tid = threadIdx.x;
  float acc = 0.f;
  for (int n = tid; n < N; n += 64)
    acc += lhs2[(b * T + t) * N + n] * rhst[(b * N + n) * T + s];
  #pragma unroll
  for (int off = 32; off > 0; off >>= 1) acc += __shfl_down(acc, off);
  if (tid == 0) Elog[bi] = acc;
}

__global__ void k_Esm(const float* Elog, float* E) {
  int b = blockIdx.x; int s = threadIdx.x;
  if (s >= T) return;
  float mx = -1e30f;
  for (int t = 0; t < T; ++t) mx = fmaxf(mx, Elog[(b * T + t) * T + s]);
  float sum = 0.f;
  for (int t = 0; t < T; ++t) sum += expf(Elog[(b * T + t) * T + s] - mx);
  float inv = 1.f / sum;
  for (int t = 0; t < T; ++t)
    E[(b * T + t) * T + s] = expf(Elog[(b * T + t) * T + s] - mx) * inv;
}

__global__ void k_EW1(const float* E, const float* W1, float* EW1) {
  int b = blockIdx.x; int t = threadIdx.x;
  if (t >= T) return;
  float acc = 0.f;
  for (int s = 0; s < T; ++s) acc += E[(b * T + t) * T + s] * W1[s];
  EW1[b * T + t] = acc;
}

// ---------------- spatial attention ----------------
__global__ void k_tmp1x(const float* x, const float* EW1, float* tmp1) {
  __shared__ float ew[T];
  int tid = threadIdx.x;
  int id = blockIdx.x * 256 + tid;       // (b*N+n)*F + f
  int b = id / (N * F);
  if (tid < T) ew[tid] = EW1[b * T + tid];
  __syncthreads();
  const float* xr = x + (size_t)id * T;
  float acc = 0.f;
  #pragma unroll
  for (int t = 0; t < T; ++t) acc += xr[t] * ew[t];
  tmp1[id] = acc;
}

__global__ void k_lhs_s(const float* tmp1, const float* W2, float* lhss) {
  int id = blockIdx.x * 256 + threadIdx.x;
  int t = id % T; int bn = id / T;
  float acc = 0.f;
  #pragma unroll
  for (int f = 0; f < F; ++f) acc += tmp1[bn * F + f] * W2[f * T + t];
  lhss[id] = acc;
}

__global__ void k_rhss(const float* w3x, const float* E, float* rhss) {
  __shared__ float Ec[T];
  int tid = threadIdx.x;
  int id = blockIdx.x * 256 + tid;       // (b*T+t)*N + m
  int m = id % N; int t = (id / N) % T; int b = id / (N * T);
  if (tid < T) Ec[tid] = E[(b * T + tid) * T + t];
  __syncthreads();
  const float* wr = w3x + ((size_t)b * N + m) * T;
  float acc = 0.f;
  #pragma unroll
  for (int tp = 0; tp < T; ++tp) acc += wr[tp] * Ec[tp];
  rhss[id] = acc;
}

__global__ void k_Slog(const float* lhss, const float* rhss, __hip_bfloat16* S) {
  __shared__ float rt[T][256];
  __shared__ float lt[16][T];
  int m0 = blockIdx.x * 256, n0 = blockIdx.y * 16, b = blockIdx.z;
  int tid = threadIdx.x;
  for (int t = 0; t < T; ++t) rt[t][tid] = rhss[((size_t)b * T + t) * N + m0 + tid];
  for (int i = tid; i < 16 * T; i += 256) {
    int n = i / T, t = i % T;
    lt[n][t] = lhss[((size_t)b * N + n0 + n) * T + t];
  }
  __syncthreads();
  #pragma unroll 4
  for (int n = 0; n < 16; ++n) {
    float acc = 0.f;
    #pragma unroll
    for (int t = 0; t < T; ++t) acc += lt[n][t] * rt[t][tid];
    S[((size_t)b * N + n0 + n) * N + m0 + tid] = __float2bfloat16(acc);
  }
}

// ---------------- column softmax stats --------------------
// Online (max, rescaled-sum) over n-segment of 128 rows; 128 columns/block.
// partials layout [seg][b][m] so writes are coalesced. grid (N/128, B, NSEG).
__global__ __launch_bounds__(256) void k_Ssum(const __hip_bfloat16* S,
                                              float* pmx, float* psm) {
  int m0 = blockIdx.x * 128; int b = blockIdx.y; int z = blockIdx.z;
  int tid = threadIdx.x;
  int lane = tid & 63, nq = tid >> 6;
  int c = m0 + lane * 2;
  float mx0 = -1e30f, sm0 = 0.f, mx1 = -1e30f, sm1 = 0.f;
  #pragma unroll 4
  for (int i = 0; i < 32; ++i) {
    int n = z * 128 + i * 4 + nq;
    unsigned u = *(const unsigned*)&S[((size_t)b * N + n) * N + c];
    float v0 = us2f((unsigned short)(u & 0xffffu));
    float v1 = us2f((unsigned short)(u >> 16));
    float nm0 = fmaxf(mx0, v0);
    sm0 = sm0 * __expf(mx0 - nm0) + __expf(v0 - nm0); mx0 = nm0;
    float nm1 = fmaxf(mx1, v1);
    sm1 = sm1 * __expf(mx1 - nm1) + __expf(v1 - nm1); mx1 = nm1;
  }
  __shared__ float lmx[4][128], lsm[4][128];
  lmx[nq][lane * 2] = mx0; lmx[nq][lane * 2 + 1] = mx1;
  lsm[nq][lane * 2] = sm0; lsm[nq][lane * 2 + 1] = sm1;
  __syncthreads();
  if (nq == 0) {
    #pragma unroll
    for (int cc2 = 0; cc2 < 2; ++cc2) {
      int col = lane * 2 + cc2;
      float M = lmx[0][col], Sg = lsm[0][col];
      #pragma unroll
      for (int s = 1; s < 4; ++s) {
        float m2 = lmx[s][col], s2 = lsm[s][col];
        float nm = fmaxf(M, m2);
        Sg = Sg * __expf(M - nm) + s2 * __expf(m2 - nm);
        M = nm;
      }
      pmx[((size_t)z * B + b) * N + m0 + col] = M;
      psm[((size_t)z * B + b) * N + m0 + col] = Sg;
    }
  }
}

// combine NSEG partials -> smax, sinv per (b,m). grid (B*N/256).
__global__ void k_Scomb(const float* pmx, const float* psm,
                        float* smax, float* sinv) {
  int id = blockIdx.x * 256 + threadIdx.x;   // b*N + m
  float M = -1e30f, Sg = 0.f;
  #pragma unroll
  for (int z = 0; z < NSEG; ++z) {
    float m2 = pmx[(size_t)z * B * N + id];
    float s2 = psm[(size_t)z * B * N + id];
    float nm = fmaxf(M, m2);
    Sg = Sg * __expf(M - nm) + s2 * __expf(m2 - nm);
    M = nm;
  }
  smax[id] = M;
  sinv[id] = 1.f / Sg;
}

// ---------------- GEMM operand prep (transpose to n-contiguous bf16) --------
// Abf[(k*Bc+bl)][m][n] = bf16(cheb[k,n,m] * softmax(S)[b,n,m]); softmax
// normalization applied inline from smax/sinv. grid (N/64, N/64, 3*Bc)
__global__ __launch_bounds__(256) void k_prepA(const float* cheb,
                                               const __hip_bfloat16* S,
                                               const float* smax,
                                               const float* sinv,
                                               unsigned short* Abf,
                                               int Bc, int b0) {
  __shared__ float Tl[64][65];
  int z = blockIdx.z;
  int k = z / Bc, bl = z % Bc, b = b0 + bl;
  int n0 = blockIdx.x * 64, m0 = blockIdx.y * 64;
  int tid = threadIdx.x;
  int j = tid & 63, i4 = tid >> 6;
  float cm = smax[(size_t)b * N + m0 + j];
  float ci = sinv[(size_t)b * N + m0 + j];
  #pragma unroll
  for (int it = 0; it < 16; ++it) {
    int i = it * 4 + i4;
    Tl[i][j] = cheb[((size_t)k * N + n0 + i) * N + m0 + j] *
               (__expf(b2f(S[((size_t)b * N + n0 + i) * N + m0 + j]) - cm) * ci);
  }
  __syncthreads();
  int i2 = (tid & 31) * 2, j8 = tid >> 5;
  #pragma unroll
  for (int it = 0; it < 8; ++it) {
    int jj = it * 8 + j8;
    unsigned u = (unsigned)f2bu(Tl[i2][jj]) | ((unsigned)f2bu(Tl[i2 + 1][jj]) << 16);
    *(unsigned*)&Abf[((size_t)z * N + m0 + jj) * N + n0 + i2] = u;
  }
}

// xT[bl][c'][n] = bf16(x[b,n,f,t]) with c' = t*32+f (kf-contiguous rk rows
// downstream). Read side identical/coalesced; only the write row is permuted.
// grid (N/64, FT/64=12, Bc)
__global__ __launch_bounds__(256) void k_prepX(const float* x, unsigned short* xT,
                                               int b0) {
  __shared__ float Tl[64][65];
  int bl = blockIdx.z, b = b0 + bl;
  int n0 = blockIdx.x * 64, c0 = blockIdx.y * 64;
  int tid = threadIdx.x;
  int j = tid & 63, i4 = tid >> 6;
  #pragma unroll
  for (int it = 0; it < 16; ++it) {
    int i = it * 4 + i4;
    Tl[i][j] = x[((size_t)b * N + n0 + i) * FT + c0 + j];
  }
  __syncthreads();
  int i2 = (tid & 31) * 2, j8 = tid >> 5;
  #pragma unroll
  for (int it = 0; it < 8; ++it) {
    int jj = it * 8 + j8;
    int c = c0 + jj;                       // old flat c = f*24+t
    int row = (c % 24) * 32 + c / 24;      // c' = t*32+f
    unsigned u = (unsigned)f2bu(Tl[i2][jj]) | ((unsigned)f2bu(Tl[i2 + 1][jj]) << 16);
    *(unsigned*)&xT[((size_t)bl * FT + row) * N + n0 + i2] = u;
  }
}

// weights -> bf16, MFMA-friendly layouts (ushort indices in wbf):
//   ThB  [o][kk=k*32+f] : [o*96 + kk]            0     .. 6143
//   tcwB [o][j*64+cc]   : [6144 + o*192 + ...]   6144  .. 18431
//   rcw pairs           : [18432 + (f>>1)*128 + o*2 + (f&1)]   .. 20479
__global__ void k_prepW(const float* Theta, const float* tcw, const float* rcw,
                        unsigned short* wbf) {
  int tid = threadIdx.x;
  for (int g = tid; g < 64 * 96; g += 256) {
    int o = g / 96, kk = g % 96;
    wbf[g] = f2bu(Theta[kk * 64 + o]);     // Theta[(k*32+f)*64 + o]
  }
  for (int g = tid; g < 64 * 192; g += 256) {
    int o = g / 192, r = g % 192;
    int jj = r / 64, cc = r % 64;
    wbf[6144 + g] = f2bu(tcw[o * 192 + cc * 3 + jj]);
  }
  for (int g = tid; g < 32 * 64; g += 256) {
    int f = g >> 6, o = g & 63;
    wbf[18432 + (f >> 1) * 128 + o * 2 + (f & 1)] = f2bu(rcw[o * 32 + f]);
  }
}

// ---------------- Chebyshev contraction: fused 3-k MFMA bf16 v3 -------------
// Staging via global_load_lds width=16. LDS linear (stride 64 ushorts);
// bank-conflict fix: per-lane XOR-swizzled GLOBAL source chunk (nh^ml),
// matching XOR ((row&7)) on the LDS read side (rule-21 both-sides pattern).
// Tile 64m x 128c x 64n; waves 2x2 (32m x 64c each). grid (6, 16, Bc).
__global__ __launch_bounds__(256) void k_gemm3(const unsigned short* Abf,
                                               const unsigned short* xT,
                                               float* rk, size_t kstride,
                                               int Bc) {
  __shared__ __align__(16) unsigned short A_l[3 * 64 * 64];   // 24576 B
  __shared__ __align__(16) unsigned short X_l[128 * 64];      // 16384 B
  int bl = blockIdx.z;
  int m0 = blockIdx.y * 64, c0 = blockIdx.x * 128;
  int tid = threadIdx.x;
  int lane = tid & 63, w = tid >> 6;
  int l15 = lane & 15, quad = lane >> 4;
  int wmi = w & 1, wci = w >> 1;
  int nh = lane & 7, ml = lane >> 3;
  int swz = nh ^ ml;                       // pre-swizzled source chunk

  f32x4 acc[3][2][4];
  #pragma unroll
  for (int k = 0; k < 3; ++k)
    #pragma unroll
    for (int mt = 0; mt < 2; ++mt)
      #pragma unroll
      for (int ct = 0; ct < 4; ++ct) acc[k][mt][ct] = (f32x4){0.f, 0.f, 0.f, 0.f};

  for (int n0 = 0; n0 < N; n0 += 64) {
    #pragma unroll
    for (int it = 0; it < 6; ++it) {               // A: 3k x 64m x 64n
      int k = it >> 1, mh = it & 1;
      int rowb = mh * 32 + w * 8;                  // wave covers rows rowb..+7
      gload16(&Abf[((size_t)(k * Bc + bl) * N + m0 + rowb + ml) * N + n0 + swz * 8],
              &A_l[(k * 64 + rowb) * 64]);
    }
    #pragma unroll
    for (int it = 0; it < 4; ++it) {               // X: 128c x 64n
      int cb = it * 32 + w * 8;
      gload16(&xT[((size_t)bl * FT + c0 + cb + ml) * N + n0 + swz * 8],
              &X_l[cb * 64]);
    }
    __syncthreads();
    #pragma unroll
    for (int ks = 0; ks < 2; ++ks) {
      short8 bfr[4];
      #pragma unroll
      for (int ct = 0; ct < 4; ++ct) {
        int row = wci * 64 + ct * 16 + l15;
        int pc = (ks * 4 + quad) ^ (row & 7);
        bfr[ct] = *(const short8*)&X_l[row * 64 + pc * 8];
      }
      #pragma unroll
      for (int k = 0; k < 3; ++k)
        #pragma unroll
        for (int mt = 0; mt < 2; ++mt) {
          int row = wmi * 32 + mt * 16 + l15;
          int pc = (ks * 4 + quad) ^ (row & 7);
          short8 af = *(const short8*)&A_l[(k * 64 + row) * 64 + pc * 8];
          #pragma unroll
          for (int ct = 0; ct < 4; ++ct)
            acc[k][mt][ct] = __builtin_amdgcn_mfma_f32_16x16x32_bf16(
                af, bfr[ct], acc[k][mt][ct], 0, 0, 0);
        }
    }
    __syncthreads();
  }
  #pragma unroll
  for (int k = 0; k < 3; ++k)
    #pragma unroll
    for (int mt = 0; mt < 2; ++mt)
      #pragma unroll
      for (int ct = 0; ct < 4; ++ct) {
        int col = c0 + wci * 64 + ct * 16 + l15;
        #pragma unroll
        for (int r = 0; r < 4; ++r) {
          int row = m0 + wmi * 32 + mt * 16 + quad * 4 + r;
          rk[k * kstride + ((size_t)bl * N + row) * FT + col] = acc[k][mt][ct][r];
        }
      }
}

// ---------------- fused theta + conv (MFMA) + residual + LN -----------------
// block 256 = 4 waves; 4 m-rows; M = (m,t) = 96 rows. Wave w owns o-tile
// [w*16, w*16+16). grid = Bc*N/4.
__global__ __launch_bounds__(256) void k_fuse(const float* rk, size_t kstride,
                                              const float* x,
                                              const unsigned short* wbf,
                                              const float* tcb, const float* rcb,
                                              const float* gam, const float* bet,
                                              float* out, int b0) {
  __shared__ __align__(16) unsigned char smem[38272];
  unsigned short* A_l = (unsigned short*)smem;      // [96][104] bf16 (phase 0-1)
  float* co_l = (float*)(smem + 13312);             // [96][65] f32 (phase 3-4)
  int tid = threadIdx.x;
  int w = tid >> 6, lane = tid & 63;
  int l15 = lane & 15, quad = lane >> 4;
  int r0l = blockIdx.x * 4;
  int o0 = w * 16;

  // B fragments from global (L1/L2-resident), register-held.
  short8 bth[3], btc[6];
  {
    int o = o0 + l15;
    #pragma unroll
    for (int ks = 0; ks < 3; ++ks)
      bth[ks] = *(const short8*)&wbf[o * 96 + ks * 32 + quad * 8];
    #pragma unroll
    for (int s = 0; s < 6; ++s)
      btc[s] = *(const short8*)&wbf[6144 + o * 192 + s * 32 + quad * 8];
  }

  // P0: A_l[(m*24+t)][k*32+f] = bf16(rk[k][r0l+m][t*32+f]); 2304 float4s.
  #pragma unroll
  for (int it = 0; it < 9; ++it) {
    int ch = it * 256 + tid;
    int k = ch / 768, r2 = ch % 768;
    int m = r2 / 192, r3 = r2 % 192;
    int t = r3 >> 3, fq = r3 & 7;
    const float4 v = *(const float4*)&rk[(size_t)k * kstride +
        (size_t)(r0l + m) * FT + t * 32 + fq * 4];
    unsigned long long pk = (unsigned long long)f2bu(v.x) |
        ((unsigned long long)f2bu(v.y) << 16) |
        ((unsigned long long)f2bu(v.z) << 32) |
        ((unsigned long long)f2bu(v.w) << 48);
    *(unsigned long long*)&A_l[(m * 24 + t) * 104 + k * 32 + fq * 4] = pk;
  }
  __syncthreads();

  // P1: theta MFMA, C[(m,t), o]; 6 M-tiles x K=3 steps.
  f32x4 th[6];
  #pragma unroll
  for (int Mt = 0; Mt < 6; ++Mt) {
    th[Mt] = (f32x4){0.f, 0.f, 0.f, 0.f};
    #pragma unroll
    for (int ks = 0; ks < 3; ++ks) {
      short8 af = *(const short8*)&A_l[(Mt * 16 + l15) * 104 + ks * 32 + quad * 8];
      th[Mt] = __builtin_amdgcn_mfma_f32_16x16x32_bf16(af, bth[ks], th[Mt], 0, 0, 0);
    }
  }
  __syncthreads();   // A_l dead; its space becomes sg_l

  // P2: sg_l[m][t'][cc] bf16, row byte-stride 128, XOR-swz key (row&7)<<4.
  // pad rows t'=0 and t'=25 zeroed (conv edge).
  #pragma unroll
  for (int e = tid; e < 512; e += 256) {
    int m = e >> 7, rr = (e >> 6) & 1, cc = e & 63;
    int rp = m * 26 + rr * 25;
    *(unsigned short*)(smem + rp * 128 + ((cc * 2) ^ ((rp & 7) << 4))) = 0;
  }
  #pragma unroll
  for (int Mt = 0; Mt < 6; ++Mt)
    #pragma unroll
    for (int r = 0; r < 4; ++r) {
      int row = Mt * 16 + quad * 4 + r;
      int m = row / 24, t = row % 24;
      int rp = m * 26 + t + 1;
      int cc = o0 + l15;
      *(unsigned short*)(smem + rp * 128 + ((cc * 2) ^ ((rp & 7) << 4))) =
          f2bu(fmaxf(th[Mt][r], 0.f));
    }
  __syncthreads();

  // P3: conv MFMA, K = 192 (j*64+cc); A row (m,t) col j*64+cc = sg[m][t+j][cc].
  f32x4 cv[6];
  #pragma unroll
  for (int Mt = 0; Mt < 6; ++Mt) {
    int row = Mt * 16 + l15;
    int m = row / 24, t = row % 24;
    cv[Mt] = (f32x4){0.f, 0.f, 0.f, 0.f};
    #pragma unroll
    for (int s = 0; s < 6; ++s) {
      int rp = m * 26 + t + (s >> 1);
      int cb = (32 * (s & 1) + quad * 8) * 2;
      short8 af = *(const short8*)(smem + rp * 128 + (cb ^ ((rp & 7) << 4)));
      cv[Mt] = __builtin_amdgcn_mfma_f32_16x16x32_bf16(af, btc[s], cv[Mt], 0, 0, 0);
    }
  }
  #pragma unroll
  for (int Mt = 0; Mt < 6; ++Mt)
    #pragma unroll
    for (int r = 0; r < 4; ++r) {
      int row = Mt * 16 + quad * 4 + r;
      co_l[row * 65 + o0 + l15] = cv[Mt][r];
    }
  __syncthreads();

  // P4: per-lane o; bias + residual (fp32) + relu + LN + store.
  int o = lane;
  float bias = tcb[o] + rcb[o];
  float acc[T];
  #pragma unroll
  for (int t = 0; t < T; ++t) acc[t] = co_l[(w * 24 + t) * 65 + o] + bias;

  size_t grow = (size_t)b0 * N + r0l + w;
  const float* xrow = x + grow * FT;
  const unsigned* rcp = (const unsigned*)(wbf + 18432);
  #pragma unroll 4
  for (int f2 = 0; f2 < 16; ++f2) {
    unsigned u = rcp[f2 * 64 + o];
    float wf0 = us2f((unsigned short)(u & 0xffffu));
    float wf1 = us2f((unsigned short)(u >> 16));
    const float4* xp0 = (const float4*)&xrow[(f2 * 2) * 24];     // wave-uniform
    const float4* xp1 = (const float4*)&xrow[(f2 * 2 + 1) * 24]; // broadcast
    #pragma unroll
    for (int q = 0; q < 6; ++q) {
      float4 v0 = xp0[q], v1 = xp1[q];
      acc[q * 4 + 0] += wf0 * v0.x + wf1 * v1.x;
      acc[q * 4 + 1] += wf0 * v0.y + wf1 * v1.y;
      acc[q * 4 + 2] += wf0 * v0.z + wf1 * v1.z;
      acc[q * 4 + 3] += wf0 * v0.w + wf1 * v1.w;
    }
  }
  float g = gam[o], be = bet[o];
  #pragma unroll
  for (int t = 0; t < T; ++t) {
    float z = fmaxf(acc[t], 0.f);
    float s = z, q = z * z;
    #pragma unroll
    for (int off = 1; off < 64; off <<= 1) {
      s += __shfl_xor(s, off);
      q += __shfl_xor(q, off);
    }
    float mu = s * (1.f / 64.f);
    float var = q * (1.f / 64.f) - mu * mu;
    acc[t] = (z - mu) * rsqrtf(var + 1e-5f) * g + be;
  }
  float* orow = out + grow * CTT + o * T;
  #pragma unroll
  for (int q = 0; q < 6; ++q)
    ((float4*)orow)[q] =
        make_float4(acc[q * 4], acc[q * 4 + 1], acc[q * 4 + 2], acc[q * 4 + 3]);
}

}  // namespace

extern "C" void kernel_launch(void* const* d_in, const int* in_sizes, int n_in,
                              void* d_out, int out_size, void* d_ws, size_t ws_size,
                              hipStream_t stream) {
  (void)in_sizes; (void)n_in; (void)out_size;
  const float* x     = (const float*)d_in[0];
  const float* W1    = (const float*)d_in[1];
  const float* W2    = (const float*)d_in[2];
  const float* W3    = (const float*)d_in[3];
  const float* U1    = (const float*)d_in[4];
  const float* U2    = (const float*)d_in[5];
  const float* U3    = (const float*)d_in[6];
  const float* cheb  = (const float*)d_in[7];
  const float* Theta = (const float*)d_in[8];
  const float* tcw   = (const float*)d_in[9];
  const float* tcb   = (const float*)d_in[10];
  const float* rcw   = (const float*)d_in[11];
  const float* rcb   = (const float*)d_in[12];
  const float* gam   = (const float*)d_in[13];
  const float* bet   = (const float*)d_in[14];
  float* out = (float*)d_out;

  // ---- runtime-adaptive workspace layout ----
  const size_t SB_BYTES = (size_t)B * N * N * 2;          // 33,554,432 (S bf16)
  const size_t WB_BYTES = 65536;                          // wbf (40960 used)
  const size_t AB_PER_B = (size_t)3 * N * N * 2;          // 6,291,456
  const size_t XT_PER_B = (size_t)FT * N * 2;             // 1,572,864
  const size_t RK_PER_B = (size_t)3 * N * FT * 4;         // 9,437,184
  const size_t SMALL = 2816384 * 4;                       // 11,265,536 B
  int Bc = 16;
  while (Bc > 1 && SB_BYTES + WB_BYTES + SMALL +
             (size_t)Bc * (AB_PER_B + XT_PER_B + RK_PER_B) > ws_size)
    Bc >>= 1;

  char* w = (char*)d_ws;
  __hip_bfloat16* Sb = (__hip_bfloat16*)w;
  unsigned short* wbf = (unsigned short*)(w + SB_BYTES);
  unsigned short* Abf = (unsigned short*)(w + SB_BYTES + WB_BYTES);
  unsigned short* xTb = (unsigned short*)(w + SB_BYTES + WB_BYTES +
                                          (size_t)Bc * AB_PER_B);
  float* rkbuf = (float*)(w + SB_BYTES + WB_BYTES +
                          (size_t)Bc * (AB_PER_B + XT_PER_B));
  size_t kstride = (size_t)Bc * N * FT;     // floats per k-bank of rk
  float* sm = (float*)(w + SB_BYTES + WB_BYTES +
                       (size_t)Bc * (AB_PER_B + XT_PER_B + RK_PER_B));
  float* lhst = sm;                       // B*T*F   = 12288
  float* lhs2 = lhst + B * T * F;         // B*T*N   = 393216
  float* rhst = lhs2 + B * T * N;         // B*N*T   = 393216
  float* w3x  = rhst + B * N * T;         // B*N*T   = 393216
  float* Elog = w3x + B * N * T;          // B*T*T   = 9216
  float* E    = Elog + B * T * T;         // B*T*T   = 9216
  float* EW1  = E + B * T * T;            // B*T     = 384
  float* tmp1 = EW1 + B * T;              // B*N*F   = 524288
  float* lhss = tmp1 + B * N * F;         // B*N*T   = 393216
  float* rhss = lhss + B * N * T;         // B*N*T   = 393216
  float* pmx  = rhss + B * N * T;         // NSEG*B*N = 131072
  float* psm  = pmx + NSEG * B * N;       // NSEG*B*N = 131072
  float* smax = psm + NSEG * B * N;       // B*N     = 16384
  float* sinv = smax + B * N;             // B*N     = 16384

  // temporal attention
  k_lhs_t<<<B * T * F, 64, 0, stream>>>(x, U1, lhst);
  k_lhs2<<<(B * T * N) / 256, 256, 0, stream>>>(lhst, U2, lhs2);
  k_fx<<<(B * N * T) / 256, 256, 0, stream>>>(x, U3, W3, rhst, w3x);
  k_Elog<<<B * T * T, 64, 0, stream>>>(lhs2, rhst, Elog);
  k_Esm<<<B, 64, 0, stream>>>(Elog, E);
  k_EW1<<<B, 64, 0, stream>>>(E, W1, EW1);

  // spatial attention (x_TAt folded out)
  k_tmp1x<<<(B * N * F) / 256, 256, 0, stream>>>(x, EW1, tmp1);
  k_lhs_s<<<(B * N * T) / 256, 256, 0, stream>>>(tmp1, W2, lhss);
  k_rhss<<<(B * N * T) / 256, 256, 0, stream>>>(w3x, E, rhss);
  k_Slog<<<dim3(N / 256, N / 16, B), 256, 0, stream>>>(lhss, rhss, Sb);
  k_Ssum<<<dim3(N / 128, B, NSEG), 256, 0, stream>>>(Sb, pmx, psm);
  k_Scomb<<<(B * N) / 256, 256, 0, stream>>>(pmx, psm, smax, sinv);

  // weight prep (once)
  k_prepW<<<1, 256, 0, stream>>>(Theta, tcw, rcw, wbf);

  // per-chunk: operand prep + fused GEMM + fused epilogue
  for (int b0 = 0; b0 < B; b0 += Bc) {
    k_prepA<<<dim3(N / 64, N / 64, 3 * Bc), 256, 0, stream>>>(cheb, Sb, smax,
                                                              sinv, Abf, Bc, b0);
    k_prepX<<<dim3(N / 64, FT / 64, Bc), 256, 0, stream>>>(x, xTb, b0);
    k_gemm3<<<dim3(FT / 128, N / 64, Bc), 256, 0, stream>>>(Abf, xTb, rkbuf,
                                                            kstride, Bc);
    k_fuse<<<Bc * N / 4, 256, 0, stream>>>(rkbuf, kstride, x, wbf, tcb, rcb,
                                           gam, bet, out, b0);
  }
}